// Round 11
// baseline (421.268 us; speedup 1.0000x reference)
//
#include <hip/hip_runtime.h>

typedef __attribute__((ext_vector_type(8))) short s8v;
typedef __attribute__((ext_vector_type(4))) short s4v;
typedef __attribute__((ext_vector_type(4))) float f4v;

#define DEV __device__ __forceinline__

DEV short b16(float f) {
  unsigned u = __builtin_bit_cast(unsigned, f);
  u = (u + 0x7fffu + ((u >> 16) & 1u)) >> 16;
  return (short)u;
}

// packed f32x2 -> bf16x2 (RNE) as one uint
DEV unsigned pk2(float a, float b) {
#if __has_builtin(__builtin_amdgcn_cvt_pk_bf16_f32)
  auto p = __builtin_amdgcn_cvt_pk_bf16_f32(a, b);
  return __builtin_bit_cast(unsigned, p);
#else
  return (unsigned)(unsigned short)b16(a) | ((unsigned)(unsigned short)b16(b) << 16);
#endif
}

DEV float fexp2(float x) {
#if __has_builtin(__builtin_amdgcn_exp2f)
  return __builtin_amdgcn_exp2f(x);
#else
  return exp2f(x);
#endif
}

// async global->LDS, 16B per lane; lds base must be wave-uniform
DEV void gl_lds16(const short* g, short* l) {
  __builtin_amdgcn_global_load_lds((const __attribute__((address_space(1))) void*)g,
                                   (__attribute__((address_space(3))) void*)l, 16, 0, 0);
}

#define WAIT_VM(N) asm volatile("s_waitcnt vmcnt(" #N ")" ::: "memory")
#define WAIT_LGKM0() asm volatile("s_waitcnt lgkmcnt(0)" ::: "memory")
#define BAR() __builtin_amdgcn_s_barrier()
#define SBAR() __builtin_amdgcn_sched_barrier(0)

// ---------------- prep: fused cast x (blocks 0..8191) + wtrans x4 (blocks 8192..10239)
__global__ __launch_bounds__(256) void prep(const float* __restrict__ x, short* __restrict__ xb,
                                            const float* __restrict__ W0, const float* __restrict__ W1,
                                            const float* __restrict__ W2, const float* __restrict__ W3,
                                            short* __restrict__ Wt) {
  const int tid = threadIdx.x;
  if (blockIdx.x < 8192) {
    int i = blockIdx.x * 256 + tid;
    float4 v = ((const float4*)x)[i];
    s4v o; o.x = b16(v.x); o.y = b16(v.y); o.z = b16(v.z); o.w = b16(v.w);
    ((s4v*)xb)[i] = o;
  } else {
    int wid = blockIdx.x - 8192;
    const int mat = wid >> 9;
    const float* W = mat == 0 ? W0 : (mat == 1 ? W1 : (mat == 2 ? W2 : W3));
    short* out = Wt + (long)mat * 1048576;
    int id = (wid & 511) * 256 + tid;
    int k8 = id >> 10;
    int n  = id & 1023;
    s8v o;
#pragma unroll
    for (int j = 0; j < 8; ++j) o[j] = b16(W[(k8 * 8 + j) * 1024 + n]);
    *(s8v*)&out[n * 1024 + k8 * 8] = o;
  }
}

// ---------------- fused QKV GEMM, 1-barrier dbuf pipeline.
// V output written in Vt [b,h,d,s] layout via coalesced LDS-transpose. XCD swizzle.
__global__ __launch_bounds__(256) void gemm_qkv(const short* __restrict__ A,
                                                const short* __restrict__ Wt,
                                                const float* __restrict__ bq,
                                                const float* __restrict__ bk,
                                                const float* __restrict__ bv,
                                                short* __restrict__ Cb,
                                                short* __restrict__ Vt, float qscale) {
  __shared__ short AB[32768];                    // [buf][A:8192|B:8192] shorts, 64 KB
  int n = blockIdx.x + 24 * blockIdx.y;          // 0..1535
  int id = (n & 7) * 192 + (n >> 3);             // bijective (1536 % 8 == 0)
  const int nx = id % 24, my = id / 24;
  const int mat = nx >> 3;
  const short* Bt = Wt + (long)mat * 1048576;
  const float* bias = mat == 0 ? bq : (mat == 1 ? bk : bv);
  short* Cout = Cb + (long)mat * 8388608;
  const float scale = mat == 0 ? qscale : 1.0f;
  const int m0 = my * 128, n0 = (nx & 7) * 128;
  const int tid = threadIdx.x;
  const int w = tid >> 6, lane = tid & 63, quad = lane >> 4, l15 = lane & 15;
  const int wm = w >> 1, wn = w & 1;
  const int lr = lane >> 3, lc = (lane & 7) * 8;
  f4v acc[4][4] = {};
  // prologue: issue step 0 into buf 0
#pragma unroll
  for (int i = 0; i < 4; ++i) {
    int c = i * 4 + w;
    int r = c * 8 + lr;
    gl_lds16(&A[(m0 + r) * 1024 + lc], &AB[c * 512]);
    gl_lds16(&Bt[(n0 + r) * 1024 + lc], &AB[8192 + c * 512]);
  }
  for (int t = 0; t < 16; ++t) {
    const int cur = (t & 1) * 16384;
    WAIT_VM(0);        // step t's loads landed (issued a full step earlier)
    WAIT_LGKM0();
    BAR();             // all waves: data ready, prev buf free
    if (t < 15) {
      const int nxt = ((t + 1) & 1) * 16384;
      const int k0 = (t + 1) * 64;
#pragma unroll
      for (int i = 0; i < 4; ++i) {
        int c = i * 4 + w;
        int r = c * 8 + lr;
        gl_lds16(&A[(m0 + r) * 1024 + k0 + lc], &AB[nxt + c * 512]);
        gl_lds16(&Bt[(n0 + r) * 1024 + k0 + lc], &AB[nxt + 8192 + c * 512]);
      }
    }
    const short* As = &AB[cur];
    const short* Bs = &AB[cur + 8192];
#pragma unroll
    for (int kk = 0; kk < 2; ++kk) {
      s8v af[4], bf[4];
#pragma unroll
      for (int mt = 0; mt < 4; ++mt) af[mt] = *(const s8v*)&As[(wm * 64 + mt * 16 + l15) * 64 + kk * 32 + quad * 8];
#pragma unroll
      for (int nt = 0; nt < 4; ++nt) bf[nt] = *(const s8v*)&Bs[(wn * 64 + nt * 16 + l15) * 64 + kk * 32 + quad * 8];
#pragma unroll
      for (int mt = 0; mt < 4; ++mt)
#pragma unroll
        for (int nt = 0; nt < 4; ++nt)
          acc[mt][nt] = __builtin_amdgcn_mfma_f32_16x16x32_bf16(af[mt], bf[nt], acc[mt][nt], 0, 0, 0);
    }
  }
  if (mat == 2) {
    __syncthreads();   // all waves done with AB before T overwrite
    // transpose 128x128 tile in LDS: T[c 0..127][s 0..127], XOR-swizzled 8-short chunks
    short* T = AB;
#pragma unroll
    for (int nt = 0; nt < 4; ++nt) {
      const int c = wn * 64 + nt * 16 + l15;
      const float bcol = bias[n0 + c];
#pragma unroll
      for (int mt = 0; mt < 4; ++mt) {
        const int sr = wm * 64 + mt * 16 + quad * 4;
#pragma unroll
        for (int r = 0; r < 4; ++r) {
          int s = sr + r;
          T[c * 128 + ((((s >> 3) ^ (c & 15))) << 3) + (s & 7)] = b16(acc[mt][nt][r] + bcol);
        }
      }
    }
    __syncthreads();
    const int b = m0 >> 11, s0 = m0 & 2047, h0 = n0 >> 6;
#pragma unroll
    for (int i = 0; i < 8; ++i) {
      int unit = tid + i * 256;
      int c = unit >> 4, s8 = unit & 15;
      s8v v = *(const s8v*)&T[c * 128 + ((s8 ^ (c & 15)) << 3)];
      *(s8v*)&Vt[(((long)(b * 16 + h0 + (c >> 6)) * 64) + (c & 63)) * 2048 + s0 + s8 * 8] = v;
    }
  } else {
#pragma unroll
    for (int nt = 0; nt < 4; ++nt) {
      const int col = n0 + wn * 64 + nt * 16 + l15;
      const float bcol = bias[col];
#pragma unroll
      for (int mt = 0; mt < 4; ++mt)
#pragma unroll
        for (int r = 0; r < 4; ++r) {
          const int row = m0 + wm * 64 + mt * 16 + quad * 4 + r;
          Cout[row * 1024 + col] = b16((acc[mt][nt][r] + bcol) * scale);
        }
    }
  }
}

// ---------------- GEMM (Wo): 1-barrier dbuf pipeline; fp32 out; XCD swizzle
__global__ __launch_bounds__(256) void gemm128(const short* __restrict__ A,
                                               const short* __restrict__ Bt,
                                               const float* __restrict__ bias,
                                               float* __restrict__ Cout) {
  __shared__ short AB[32768];
  int n = blockIdx.x + 8 * blockIdx.y;           // 0..511
  int id = (n & 7) * 64 + (n >> 3);              // bijective (512 % 8 == 0)
  const int m0 = (id >> 3) * 128, n0 = (id & 7) * 128;
  const int tid = threadIdx.x;
  const int w = tid >> 6, lane = tid & 63, quad = lane >> 4, l15 = lane & 15;
  const int wm = w >> 1, wn = w & 1;
  const int lr = lane >> 3, lc = (lane & 7) * 8;
  f4v acc[4][4] = {};
#pragma unroll
  for (int i = 0; i < 4; ++i) {
    int c = i * 4 + w;
    int r = c * 8 + lr;
    gl_lds16(&A[(m0 + r) * 1024 + lc], &AB[c * 512]);
    gl_lds16(&Bt[(n0 + r) * 1024 + lc], &AB[8192 + c * 512]);
  }
  for (int t = 0; t < 16; ++t) {
    const int cur = (t & 1) * 16384;
    WAIT_VM(0);
    WAIT_LGKM0();
    BAR();
    if (t < 15) {
      const int nxt = ((t + 1) & 1) * 16384;
      const int k0 = (t + 1) * 64;
#pragma unroll
      for (int i = 0; i < 4; ++i) {
        int c = i * 4 + w;
        int r = c * 8 + lr;
        gl_lds16(&A[(m0 + r) * 1024 + k0 + lc], &AB[nxt + c * 512]);
        gl_lds16(&Bt[(n0 + r) * 1024 + k0 + lc], &AB[nxt + 8192 + c * 512]);
      }
    }
    const short* As = &AB[cur];
    const short* Bs = &AB[cur + 8192];
#pragma unroll
    for (int kk = 0; kk < 2; ++kk) {
      s8v af[4], bf[4];
#pragma unroll
      for (int mt = 0; mt < 4; ++mt) af[mt] = *(const s8v*)&As[(wm * 64 + mt * 16 + l15) * 64 + kk * 32 + quad * 8];
#pragma unroll
      for (int nt = 0; nt < 4; ++nt) bf[nt] = *(const s8v*)&Bs[(wn * 64 + nt * 16 + l15) * 64 + kk * 32 + quad * 8];
#pragma unroll
      for (int mt = 0; mt < 4; ++mt)
#pragma unroll
        for (int nt = 0; nt < 4; ++nt)
          acc[mt][nt] = __builtin_amdgcn_mfma_f32_16x16x32_bf16(af[mt], bf[nt], acc[mt][nt], 0, 0, 0);
    }
  }
#pragma unroll
  for (int nt = 0; nt < 4; ++nt) {
    const int col = n0 + wn * 64 + nt * 16 + l15;
    const float bcol = bias[col];
#pragma unroll
    for (int mt = 0; mt < 4; ++mt)
#pragma unroll
      for (int r = 0; r < 4; ++r) {
        const int row = m0 + wm * 64 + mt * 16 + quad * 4 + r;
        Cout[row * 1024 + col] = acc[mt][nt][r] + bcol;
      }
  }
}

// ---------------- fused attention v11: q-sliced score (wave-private P) + dbuf K/V +
// ONE barrier per tile. Wave w owns q rows [w*16,w*16+16) end-to-end: score = own 2
// Q-frags (B) x ALL 128 K rows (A, 16 MFMA); P rows wave-private in LDS (intra-wave
// lgkm sync only); PV = 20 MFMA incl. l-via-MFMA. K/V double-buffered, mean_probs
// ledger: loads issued after BAR(t), waited at top of t+1 (full-tile latency cover).
// LDS 80KB -> 2 blocks/CU. XCD swizzle retained.
__global__ __launch_bounds__(256, 2) void attn_ctx(const short* __restrict__ Q, const short* __restrict__ K,
                                                   const short* __restrict__ Vt,
                                                   float* __restrict__ rbuf, short* __restrict__ ctx) {
  __shared__ __align__(16) char smem[81920];
  // Ks[2]: [128 kpos][64 d] @0/16384 ; Vs[2]: [64 d][128 kpos] @32768/49152 ; Ps @65536
  short* Ps = (short*)(smem + 65536);       // [64 q][128 kpos] swizzled, wave-private rows
  short* Qs = Ps;                           // alias: Qs dead after frag hoist
  int nlin = blockIdx.x + 32 * (blockIdx.y + 16 * blockIdx.z);   // 0..2047
  int bid = (nlin & 7) * 256 + (nlin >> 3);                      // bijective (2048 % 8 == 0)
  const int q64 = bid & 31, h = (bid >> 5) & 15, b = bid >> 9;
  const int tid = threadIdx.x, w = tid >> 6, lane = tid & 63, quad = lane >> 4, l15 = lane & 15;
  const int bh = b * 16 + h, q0 = q64 * 64;

  const short* kbase = &K[((long)(b * 2048) * 16 + h) * 64];
  const short* vbase = &Vt[(long)(bh * 64) * 2048];
  const int krow = w * 8 + (lane >> 3);
  const short* ksrc = kbase + krow * 1024 + (((lane & 7) ^ (lane >> 3)) << 3);
  const int vrow = w * 4 + (lane >> 4);
  const short* vsrc = vbase + vrow * 2048 + (((lane & 15) ^ vrow) << 3);

  // prologue: issue K(0)+V(0) into buf 0 (cooperative, v8 patterns)
#pragma unroll
  for (int i = 0; i < 4; ++i) gl_lds16(ksrc + i * 32768, (short*)smem + (i * 4 + w) * 512);
#pragma unroll
  for (int i = 0; i < 4; ++i) gl_lds16(vsrc + i * 32768, (short*)(smem + 32768) + (i * 4 + w) * 512);

  // stage Q tile (64x64) swizzled (reg roundtrip; once per kernel)
#pragma unroll
  for (int i = 0; i < 2; ++i) {
    int c = tid + i * 256;
    int r = c >> 3, cc = c & 7;
    *(s8v*)&Qs[r * 64 + (((cc ^ (r & 7))) << 3)] =
        *(const s8v*)&Q[((b * 2048 + q0 + r) * 16 + h) * 64 + cc * 8];
  }
  __syncthreads();   // drains all vm (K0,V0,Q) + lgkm; Q staged
  // hoist own-wave Q B-frags (cols q = w*16 + l15)
  const int qrow = w * 16 + l15;
  s8v qb0 = *(const s8v*)&Qs[qrow * 64 + ((quad ^ (qrow & 7)) << 3)];
  s8v qb1 = *(const s8v*)&Qs[qrow * 64 + (((4 + quad) ^ (qrow & 7)) << 3)];
  WAIT_LGKM0(); SBAR();   // Qs reads captured before Ps overwrite (rule #18)

  f4v o[4] = {};
  f4v lf = {};
  s8v ones;
#pragma unroll
  for (int j = 0; j < 8; ++j) ones[j] = (short)0x3F80;   // bf16 1.0

  for (int kt = 0; kt < 16; ++kt) {
    const int cur = (kt & 1) * 16384;
    const short* KsC = (const short*)(smem + cur);
    const short* VsC = (const short*)(smem + 32768 + cur);
    WAIT_VM(0);        // tile kt's 8 loads landed (issued a full tile earlier)
    WAIT_LGKM0();      // own prior-tile ds reads captured (buf^1 free)
    BAR();             // all waves aligned
    if (kt < 15) {
      const int nxt = ((kt + 1) & 1) * 16384;
#pragma unroll
      for (int i = 0; i < 4; ++i)
        gl_lds16(ksrc + (kt + 1) * 131072 + i * 32768, (short*)(smem + nxt) + (i * 4 + w) * 512);
#pragma unroll
      for (int i = 0; i < 4; ++i)
        gl_lds16(vsrc + (kt + 1) * 128 + i * 32768, (short*)(smem + 32768 + nxt) + (i * 4 + w) * 512);
    }
    // score: own 16 q (B=qb), ALL 128 kpos (A=K rows)
#pragma unroll
    for (int ktile = 0; ktile < 8; ++ktile) {
      int kr = ktile * 16 + l15;
      s8v a0 = *(const s8v*)&KsC[kr * 64 + ((quad ^ (kr & 7)) << 3)];
      s8v a1 = *(const s8v*)&KsC[kr * 64 + (((4 + quad) ^ (kr & 7)) << 3)];
      f4v st = {};
      st = __builtin_amdgcn_mfma_f32_16x16x32_bf16(a0, qb0, st, 0, 0, 0);
      st = __builtin_amdgcn_mfma_f32_16x16x32_bf16(a1, qb1, st, 0, 0, 0);
      float e0 = fexp2(st[0]), e1 = fexp2(st[1]);
      float e2 = fexp2(st[2]), e3 = fexp2(st[3]);
      uint2 pp; pp.x = pk2(e0, e1); pp.y = pk2(e2, e3);
      // lane: q=qrow, kpos = ktile*16 + quad*4 + r -> 16B chunk = ktile*2 + (quad>>1)
      int chunk = (ktile * 2 + (quad >> 1)) ^ l15;
      *(uint2*)&Ps[qrow * 128 + (chunk << 3) + (quad & 1) * 4] = pp;
    }
    WAIT_LGKM0(); SBAR();          // own Ps writes visible to own reads (rule #18)
    // PV: own 16 q rows, full 128 kpos
#pragma unroll
    for (int kk = 0; kk < 4; ++kk) {
      s8v a = *(const s8v*)&Ps[qrow * 128 + (((kk * 4 + quad) ^ l15) << 3)];
#pragma unroll
      for (int dt = 0; dt < 4; ++dt) {
        int d = dt * 16 + l15;
        s8v vb = *(const s8v*)&VsC[d * 128 + (((kk * 4 + quad) ^ (d & 15)) << 3)];
        o[dt] = __builtin_amdgcn_mfma_f32_16x16x32_bf16(a, vb, o[dt], 0, 0, 0);
      }
      lf = __builtin_amdgcn_mfma_f32_16x16x32_bf16(a, ones, lf, 0, 0, 0);
    }
  }

  // lf[r] = l for q = w*16 + quad*4 + r (replicated across l15). No reduce needed.
  float rv[4];
#pragma unroll
  for (int r = 0; r < 4; ++r) rv[r] = 1.0f / lf[r];
  if (l15 == 0) {
    f4v t; t[0] = rv[0]; t[1] = rv[1]; t[2] = rv[2]; t[3] = rv[3];
    *(f4v*)&rbuf[bh * 2048 + q0 + w * 16 + quad * 4] = t;
  }
#pragma unroll
  for (int dt = 0; dt < 4; ++dt)
#pragma unroll
    for (int r = 0; r < 4; ++r) {
      int sq = q0 + w * 16 + quad * 4 + r;
      ctx[((b * 2048 + sq) * 16 + h) * 64 + dt * 16 + l15] = b16(o[dt][r] * rv[r]);
    }
}

// ---------------- mean over heads of probs -> [b, q, k] fp32
// ONE barrier per h (dbuf; DMA h+1 issued after top barrier, waited next iter).
__global__ __launch_bounds__(256) void mean_probs(const short* __restrict__ Q, const short* __restrict__ K,
                                                  const float* __restrict__ rbuf, float* __restrict__ outm) {
  __shared__ __align__(16) short Qs[2][8192];   // [128 q][64 d] swizzled, dbuf
  __shared__ __align__(16) short Ks[2][8192];   // [128 k][64 d] swizzled, dbuf
  __shared__ __align__(16) float r_all[2048];   // [16 h][128 q]
  int nlin = blockIdx.x + 16 * (blockIdx.y + 16 * blockIdx.z);   // 0..1023
  int bid = (nlin & 7) * 128 + (nlin >> 3);                      // bijective (1024 % 8 == 0)
  const int k128 = bid & 15, q128 = (bid >> 4) & 15, b = bid >> 8;
  const int tid = threadIdx.x, w = tid >> 6, lane = tid & 63, quad = lane >> 4, l15 = lane & 15;
  f4v mn[2][8] = {};
  const int mrow = w * 8 + (lane >> 3);
  const int mck8 = ((lane & 7) ^ (lane >> 3)) << 3;
  const short* qsrc = Q + ((long)(b * 2048 + q128 * 128 + mrow) * 16) * 64 + mck8;
  const short* ksrc = K + ((long)(b * 2048 + k128 * 128 + mrow) * 16) * 64 + mck8;
  const float* rb = rbuf + (long)(b * 16) * 2048 + q128 * 128;
#pragma unroll
  for (int i = 0; i < 2; ++i) {
    int hh = i * 8 + w * 2 + (lane >> 5);
    gl_lds16((const short*)(rb + hh * 2048 + (lane & 31) * 4), (short*)r_all + (i * 4 + w) * 512);
  }
#pragma unroll
  for (int i = 0; i < 4; ++i) gl_lds16(qsrc + i * 32768, &Qs[0][(i * 4 + w) * 512]);
#pragma unroll
  for (int i = 0; i < 4; ++i) gl_lds16(ksrc + i * 32768, &Ks[0][(i * 4 + w) * 512]);

  for (int h = 0; h < 16; ++h) {
    const int cur = h & 1;
    WAIT_VM(0);     // h's loads (+r_all at h=0) landed (issued a full h-step ago)
    BAR();          // all waves: landed + done with buf cur^1
    if (h < 15) {
#pragma unroll
      for (int i = 0; i < 4; ++i) gl_lds16(qsrc + (h + 1) * 64 + i * 32768, &Qs[cur ^ 1][(i * 4 + w) * 512]);
#pragma unroll
      for (int i = 0; i < 4; ++i) gl_lds16(ksrc + (h + 1) * 64 + i * 32768, &Ks[cur ^ 1][(i * 4 + w) * 512]);
    }
    s8v aq[2][2];
#pragma unroll
    for (int qt = 0; qt < 2; ++qt) {
      int r = w * 32 + qt * 16 + l15;
      aq[qt][0] = *(const s8v*)&Qs[cur][r * 64 + ((quad ^ (r & 7)) << 3)];
      aq[qt][1] = *(const s8v*)&Qs[cur][r * 64 + (((4 + quad) ^ (r & 7)) << 3)];
    }
    float rr[2][4];
#pragma unroll
    for (int qt = 0; qt < 2; ++qt)
#pragma unroll
      for (int r = 0; r < 4; ++r) rr[qt][r] = r_all[h * 128 + w * 32 + qt * 16 + quad * 4 + r];
#pragma unroll
    for (int ktile = 0; ktile < 8; ++ktile) {
      int kr = ktile * 16 + l15;
      s8v b0 = *(const s8v*)&Ks[cur][kr * 64 + ((quad ^ (kr & 7)) << 3)];
      s8v b1 = *(const s8v*)&Ks[cur][kr * 64 + (((4 + quad) ^ (kr & 7)) << 3)];
#pragma unroll
      for (int qt = 0; qt < 2; ++qt) {
        f4v sc = {};
        sc = __builtin_amdgcn_mfma_f32_16x16x32_bf16(aq[qt][0], b0, sc, 0, 0, 0);
        sc = __builtin_amdgcn_mfma_f32_16x16x32_bf16(aq[qt][1], b1, sc, 0, 0, 0);
#pragma unroll
        for (int r = 0; r < 4; ++r)
          mn[qt][ktile][r] += fexp2(sc[r]) * rr[qt][r];
      }
    }
  }
#pragma unroll
  for (int qt = 0; qt < 2; ++qt)
#pragma unroll
    for (int ktile = 0; ktile < 8; ++ktile)
#pragma unroll
      for (int r = 0; r < 4; ++r) {
        long qrow = q128 * 128 + w * 32 + qt * 16 + quad * 4 + r;
        outm[((long)b * 2048 + qrow) * 2048 + k128 * 128 + ktile * 16 + l15] = mn[qt][ktile][r] * 0.0625f;
      }
}

extern "C" void kernel_launch(void* const* d_in, const int* in_sizes, int n_in,
                              void* d_out, int out_size, void* d_ws, size_t ws_size,
                              hipStream_t stream) {
  (void)in_sizes; (void)n_in; (void)out_size; (void)ws_size;
  const float* x  = (const float*)d_in[0];
  const float* Wq = (const float*)d_in[1];
  const float* bq = (const float*)d_in[2];
  const float* Wk = (const float*)d_in[3];
  const float* bk = (const float*)d_in[4];
  const float* Wv = (const float*)d_in[5];
  const float* bv = (const float*)d_in[6];
  const float* Wo = (const float*)d_in[7];
  const float* bo = (const float*)d_in[8];
  float* out  = (float*)d_out;
  float* outm = out + 8388608;

  char* ws = (char*)d_ws;
  short* xb  = (short*)(ws);                 // 16 MB (reused as ctx)
  short* Wqt = (short*)(ws + 16777216);      // Wqt,Wkt,Wvt,Wot contiguous 2MB each
  short* Wot = (short*)(ws + 23068672);
  short* Qb  = (short*)(ws + 25165824);      // Qb,Kb contiguous 16 MB each
  short* Kb  = (short*)(ws + 41943040);
  short* Vt  = (short*)(ws + 75497472);      // 16 MB, written directly by gemm_qkv
  float* rbuf = (float*)(ws + 58720256);     // in unused slot
  short* ctx = xb;                           // alias: xb dead after QKV GEMMs

  const float C2 = 0.18033688011112042f;     // (1/8) * log2(e), folded into Q projection

  prep<<<10240, 256, 0, stream>>>(x, xb, Wq, Wk, Wv, Wo, Wqt);
  gemm_qkv<<<dim3(24, 64), 256, 0, stream>>>(xb, Wqt, bq, bk, bv, Qb, Vt, C2);
  attn_ctx<<<dim3(32, 16, 4), 256, 0, stream>>>(Qb, Kb, Vt, rbuf, ctx);
  mean_probs<<<dim3(16, 16, 4), 256, 0, stream>>>(Qb, Kb, rbuf, outm);
  gemm128<<<dim3(8, 64), 256, 0, stream>>>(ctx, Wot, bo, out);
}

// Round 12
// 395.193 us; speedup vs baseline: 1.0660x; 1.0660x over previous
//
#include <hip/hip_runtime.h>

typedef __attribute__((ext_vector_type(8))) short s8v;
typedef __attribute__((ext_vector_type(4))) short s4v;
typedef __attribute__((ext_vector_type(4))) float f4v;

#define DEV __device__ __forceinline__

DEV short b16(float f) {
  unsigned u = __builtin_bit_cast(unsigned, f);
  u = (u + 0x7fffu + ((u >> 16) & 1u)) >> 16;
  return (short)u;
}

// packed f32x2 -> bf16x2 (RNE) as one uint
DEV unsigned pk2(float a, float b) {
#if __has_builtin(__builtin_amdgcn_cvt_pk_bf16_f32)
  auto p = __builtin_amdgcn_cvt_pk_bf16_f32(a, b);
  return __builtin_bit_cast(unsigned, p);
#else
  return (unsigned)(unsigned short)b16(a) | ((unsigned)(unsigned short)b16(b) << 16);
#endif
}

DEV float fexp2(float x) {
#if __has_builtin(__builtin_amdgcn_exp2f)
  return __builtin_amdgcn_exp2f(x);
#else
  return exp2f(x);
#endif
}

// async global->LDS, 16B per lane; lds base must be wave-uniform
DEV void gl_lds16(const short* g, short* l) {
  __builtin_amdgcn_global_load_lds((const __attribute__((address_space(1))) void*)g,
                                   (__attribute__((address_space(3))) void*)l, 16, 0, 0);
}

#define WAIT_VM(N) asm volatile("s_waitcnt vmcnt(" #N ")" ::: "memory")
#define WAIT_LGKM0() asm volatile("s_waitcnt lgkmcnt(0)" ::: "memory")
#define BAR() __builtin_amdgcn_s_barrier()

// ---------------- prep: fused cast x (blocks 0..8191) + wtrans x4 (blocks 8192..10239)
__global__ __launch_bounds__(256) void prep(const float* __restrict__ x, short* __restrict__ xb,
                                            const float* __restrict__ W0, const float* __restrict__ W1,
                                            const float* __restrict__ W2, const float* __restrict__ W3,
                                            short* __restrict__ Wt) {
  const int tid = threadIdx.x;
  if (blockIdx.x < 8192) {
    int i = blockIdx.x * 256 + tid;
    float4 v = ((const float4*)x)[i];
    s4v o; o.x = b16(v.x); o.y = b16(v.y); o.z = b16(v.z); o.w = b16(v.w);
    ((s4v*)xb)[i] = o;
  } else {
    int wid = blockIdx.x - 8192;
    const int mat = wid >> 9;
    const float* W = mat == 0 ? W0 : (mat == 1 ? W1 : (mat == 2 ? W2 : W3));
    short* out = Wt + (long)mat * 1048576;
    int id = (wid & 511) * 256 + tid;
    int k8 = id >> 10;
    int n  = id & 1023;
    s8v o;
#pragma unroll
    for (int j = 0; j < 8; ++j) o[j] = b16(W[(k8 * 8 + j) * 1024 + n]);
    *(s8v*)&out[n * 1024 + k8 * 8] = o;
  }
}

// ---------------- fused QKV GEMM, 1-barrier dbuf pipeline.
// V output written in Vt [b,h,d,s] layout via coalesced LDS-transpose. XCD swizzle.
__global__ __launch_bounds__(256) void gemm_qkv(const short* __restrict__ A,
                                                const short* __restrict__ Wt,
                                                const float* __restrict__ bq,
                                                const float* __restrict__ bk,
                                                const float* __restrict__ bv,
                                                short* __restrict__ Cb,
                                                short* __restrict__ Vt, float qscale) {
  __shared__ short AB[32768];                    // [buf][A:8192|B:8192] shorts, 64 KB
  int n = blockIdx.x + 24 * blockIdx.y;          // 0..1535
  int id = (n & 7) * 192 + (n >> 3);             // bijective (1536 % 8 == 0)
  const int nx = id % 24, my = id / 24;
  const int mat = nx >> 3;
  const short* Bt = Wt + (long)mat * 1048576;
  const float* bias = mat == 0 ? bq : (mat == 1 ? bk : bv);
  short* Cout = Cb + (long)mat * 8388608;
  const float scale = mat == 0 ? qscale : 1.0f;
  const int m0 = my * 128, n0 = (nx & 7) * 128;
  const int tid = threadIdx.x;
  const int w = tid >> 6, lane = tid & 63, quad = lane >> 4, l15 = lane & 15;
  const int wm = w >> 1, wn = w & 1;
  const int lr = lane >> 3, lc = (lane & 7) * 8;
  f4v acc[4][4] = {};
  // prologue: issue step 0 into buf 0
#pragma unroll
  for (int i = 0; i < 4; ++i) {
    int c = i * 4 + w;
    int r = c * 8 + lr;
    gl_lds16(&A[(m0 + r) * 1024 + lc], &AB[c * 512]);
    gl_lds16(&Bt[(n0 + r) * 1024 + lc], &AB[8192 + c * 512]);
  }
  for (int t = 0; t < 16; ++t) {
    const int cur = (t & 1) * 16384;
    WAIT_VM(0);        // step t's loads landed (issued a full step earlier)
    WAIT_LGKM0();
    BAR();             // all waves: data ready, prev buf free
    if (t < 15) {
      const int nxt = ((t + 1) & 1) * 16384;
      const int k0 = (t + 1) * 64;
#pragma unroll
      for (int i = 0; i < 4; ++i) {
        int c = i * 4 + w;
        int r = c * 8 + lr;
        gl_lds16(&A[(m0 + r) * 1024 + k0 + lc], &AB[nxt + c * 512]);
        gl_lds16(&Bt[(n0 + r) * 1024 + k0 + lc], &AB[nxt + 8192 + c * 512]);
      }
    }
    const short* As = &AB[cur];
    const short* Bs = &AB[cur + 8192];
#pragma unroll
    for (int kk = 0; kk < 2; ++kk) {
      s8v af[4], bf[4];
#pragma unroll
      for (int mt = 0; mt < 4; ++mt) af[mt] = *(const s8v*)&As[(wm * 64 + mt * 16 + l15) * 64 + kk * 32 + quad * 8];
#pragma unroll
      for (int nt = 0; nt < 4; ++nt) bf[nt] = *(const s8v*)&Bs[(wn * 64 + nt * 16 + l15) * 64 + kk * 32 + quad * 8];
#pragma unroll
      for (int mt = 0; mt < 4; ++mt)
#pragma unroll
        for (int nt = 0; nt < 4; ++nt)
          acc[mt][nt] = __builtin_amdgcn_mfma_f32_16x16x32_bf16(af[mt], bf[nt], acc[mt][nt], 0, 0, 0);
    }
  }
  if (mat == 2) {
    __syncthreads();   // all waves done with AB before T overwrite
    // transpose 128x128 tile in LDS: T[c 0..127][s 0..127], XOR-swizzled 8-short chunks
    short* T = AB;
#pragma unroll
    for (int nt = 0; nt < 4; ++nt) {
      const int c = wn * 64 + nt * 16 + l15;
      const float bcol = bias[n0 + c];
#pragma unroll
      for (int mt = 0; mt < 4; ++mt) {
        const int sr = wm * 64 + mt * 16 + quad * 4;
#pragma unroll
        for (int r = 0; r < 4; ++r) {
          int s = sr + r;
          T[c * 128 + ((((s >> 3) ^ (c & 15))) << 3) + (s & 7)] = b16(acc[mt][nt][r] + bcol);
        }
      }
    }
    __syncthreads();
    const int b = m0 >> 11, s0 = m0 & 2047, h0 = n0 >> 6;
#pragma unroll
    for (int i = 0; i < 8; ++i) {
      int unit = tid + i * 256;
      int c = unit >> 4, s8 = unit & 15;
      s8v v = *(const s8v*)&T[c * 128 + ((s8 ^ (c & 15)) << 3)];
      *(s8v*)&Vt[(((long)(b * 16 + h0 + (c >> 6)) * 64) + (c & 63)) * 2048 + s0 + s8 * 8] = v;
    }
  } else {
#pragma unroll
    for (int nt = 0; nt < 4; ++nt) {
      const int col = n0 + wn * 64 + nt * 16 + l15;
      const float bcol = bias[col];
#pragma unroll
      for (int mt = 0; mt < 4; ++mt)
#pragma unroll
        for (int r = 0; r < 4; ++r) {
          const int row = m0 + wm * 64 + mt * 16 + quad * 4 + r;
          Cout[row * 1024 + col] = b16((acc[mt][nt][r] + bcol) * scale);
        }
    }
  }
}

// ---------------- GEMM (Wo): 1-barrier dbuf pipeline; fp32 out; XCD swizzle
__global__ __launch_bounds__(256) void gemm128(const short* __restrict__ A,
                                               const short* __restrict__ Bt,
                                               const float* __restrict__ bias,
                                               float* __restrict__ Cout) {
  __shared__ short AB[32768];
  int n = blockIdx.x + 8 * blockIdx.y;           // 0..511
  int id = (n & 7) * 64 + (n >> 3);              // bijective (512 % 8 == 0)
  const int m0 = (id >> 3) * 128, n0 = (id & 7) * 128;
  const int tid = threadIdx.x;
  const int w = tid >> 6, lane = tid & 63, quad = lane >> 4, l15 = lane & 15;
  const int wm = w >> 1, wn = w & 1;
  const int lr = lane >> 3, lc = (lane & 7) * 8;
  f4v acc[4][4] = {};
#pragma unroll
  for (int i = 0; i < 4; ++i) {
    int c = i * 4 + w;
    int r = c * 8 + lr;
    gl_lds16(&A[(m0 + r) * 1024 + lc], &AB[c * 512]);
    gl_lds16(&Bt[(n0 + r) * 1024 + lc], &AB[8192 + c * 512]);
  }
  for (int t = 0; t < 16; ++t) {
    const int cur = (t & 1) * 16384;
    WAIT_VM(0);
    WAIT_LGKM0();
    BAR();
    if (t < 15) {
      const int nxt = ((t + 1) & 1) * 16384;
      const int k0 = (t + 1) * 64;
#pragma unroll
      for (int i = 0; i < 4; ++i) {
        int c = i * 4 + w;
        int r = c * 8 + lr;
        gl_lds16(&A[(m0 + r) * 1024 + k0 + lc], &AB[nxt + c * 512]);
        gl_lds16(&Bt[(n0 + r) * 1024 + k0 + lc], &AB[nxt + 8192 + c * 512]);
      }
    }
    const short* As = &AB[cur];
    const short* Bs = &AB[cur + 8192];
#pragma unroll
    for (int kk = 0; kk < 2; ++kk) {
      s8v af[4], bf[4];
#pragma unroll
      for (int mt = 0; mt < 4; ++mt) af[mt] = *(const s8v*)&As[(wm * 64 + mt * 16 + l15) * 64 + kk * 32 + quad * 8];
#pragma unroll
      for (int nt = 0; nt < 4; ++nt) bf[nt] = *(const s8v*)&Bs[(wn * 64 + nt * 16 + l15) * 64 + kk * 32 + quad * 8];
#pragma unroll
      for (int mt = 0; mt < 4; ++mt)
#pragma unroll
        for (int nt = 0; nt < 4; ++nt)
          acc[mt][nt] = __builtin_amdgcn_mfma_f32_16x16x32_bf16(af[mt], bf[nt], acc[mt][nt], 0, 0, 0);
    }
  }
#pragma unroll
  for (int nt = 0; nt < 4; ++nt) {
    const int col = n0 + wn * 64 + nt * 16 + l15;
    const float bcol = bias[col];
#pragma unroll
    for (int mt = 0; mt < 4; ++mt)
#pragma unroll
      for (int r = 0; r < 4; ++r) {
        const int row = m0 + wm * 64 + mt * 16 + quad * 4 + r;
        Cout[row * 1024 + col] = acc[mt][nt][r] + bcol;
      }
  }
}

// ---------------- fused attention v8 (known-good): counted-vmcnt pipeline +
// l-via-MFMA + XCD swizzle. KVBLK=128, 3 blocks/CU. No setprio (measured harmful).
__global__ __launch_bounds__(256, 3) void attn_ctx(const short* __restrict__ Q, const short* __restrict__ K,
                                                   const short* __restrict__ Vt,
                                                   float* __restrict__ rbuf, short* __restrict__ ctx) {
  __shared__ __align__(16) char smem[49152];
  short* Ks = (short*)smem;                 // [128 kpos][64 d]   swizzled, 16384 B
  short* Vs = (short*)(smem + 16384);       // [64 d][128 kpos]   swizzled, 16384 B
  short* Ps = (short*)(smem + 32768);       // [64 q][128 kpos]   swizzled, 16384 B
  short* Qs = Ps;                           // alias: Qs dead after frag hoist
  int nlin = blockIdx.x + 32 * (blockIdx.y + 16 * blockIdx.z);   // 0..2047
  int bid = (nlin & 7) * 256 + (nlin >> 3);                      // bijective (2048 % 8 == 0)
  const int q64 = bid & 31, h = (bid >> 5) & 15, b = bid >> 9;
  const int tid = threadIdx.x, w = tid >> 6, lane = tid & 63, quad = lane >> 4, l15 = lane & 15;
  const int bh = b * 16 + h, q0 = q64 * 64;

  // stage Q tile (64x64) swizzled (reg roundtrip; once per kernel)
#pragma unroll
  for (int i = 0; i < 2; ++i) {
    int c = tid + i * 256;
    int r = c >> 3, cc = c & 7;
    *(s8v*)&Qs[r * 64 + (((cc ^ (r & 7))) << 3)] =
        *(const s8v*)&Q[((b * 2048 + q0 + r) * 16 + h) * 64 + cc * 8];
  }
  __syncthreads();   // full drain: vmcnt=0 after this
  // hoist Q fragments (B-operand of St = K·Q^T), all 64 q cols
  s8v qf[4][2];
#pragma unroll
  for (int nt = 0; nt < 4; ++nt) {
    int r = nt * 16 + l15;
    qf[nt][0] = *(const s8v*)&Qs[r * 64 + ((quad ^ (r & 7)) << 3)];
    qf[nt][1] = *(const s8v*)&Qs[r * 64 + (((4 + quad) ^ (r & 7)) << 3)];
  }
  const short* kbase = &K[((long)(b * 2048) * 16 + h) * 64];
  const short* vbase = &Vt[(long)(bh * 64) * 2048];
  const int krow = w * 8 + (lane >> 3);
  const short* ksrc = kbase + krow * 1024 + (((lane & 7) ^ (lane >> 3)) << 3);
  const int vrow = w * 4 + (lane >> 4);
  const short* vsrc = vbase + vrow * 2048 + (((lane & 15) ^ vrow) << 3);
  f4v o[4] = {};
  f4v lf = {};
  s8v ones;
#pragma unroll
  for (int j = 0; j < 8; ++j) ones[j] = (short)0x3F80;   // bf16 1.0

  // prologue: issue K(0) group (4), then V(0) group (4)
#pragma unroll
  for (int i = 0; i < 4; ++i) gl_lds16(ksrc + i * 32768, &Ks[(i * 4 + w) * 512]);
#pragma unroll
  for (int i = 0; i < 4; ++i) gl_lds16(vsrc + i * 32768, &Vs[(i * 4 + w) * 512]);
  WAIT_LGKM0();   // qf reads complete before first barrier

  for (int kt = 0; kt < 16; ++kt) {
    WAIT_VM(4);                     // own K(kt) retired (V(kt) may remain)
    BAR();                          // all waves' K DMA landed
    // score phase: wave w computes St rows kpos [w*32, w*32+32), all 64 q
#pragma unroll
    for (int mt = 0; mt < 2; ++mt) {
      int kr = w * 32 + mt * 16 + l15;
      s8v a0 = *(const s8v*)&Ks[kr * 64 + ((quad ^ (kr & 7)) << 3)];
      s8v a1 = *(const s8v*)&Ks[kr * 64 + (((4 + quad) ^ (kr & 7)) << 3)];
#pragma unroll
      for (int nt = 0; nt < 4; ++nt) {
        f4v st = {};
        st = __builtin_amdgcn_mfma_f32_16x16x32_bf16(a0, qf[nt][0], st, 0, 0, 0);
        st = __builtin_amdgcn_mfma_f32_16x16x32_bf16(a1, qf[nt][1], st, 0, 0, 0);
        float e0 = fexp2(st[0]), e1 = fexp2(st[1]);
        float e2 = fexp2(st[2]), e3 = fexp2(st[3]);
        uint2 pp; pp.x = pk2(e0, e1); pp.y = pk2(e2, e3);
        int q = nt * 16 + l15;
        int chunk = (w * 4 + mt * 2 + (quad >> 1)) ^ l15;
        *(uint2*)&Ps[q * 128 + (chunk << 3) + (quad & 1) * 4] = pp;
      }
    }
    WAIT_LGKM0();                   // Ps writes + Ks reads done
    BAR();                          // Ks free, Ps visible
    if (kt < 15) {
#pragma unroll
      for (int i = 0; i < 4; ++i) gl_lds16(ksrc + (kt + 1) * 131072 + i * 32768, &Ks[(i * 4 + w) * 512]);
      WAIT_VM(4);                   // V(kt) retired (K(kt+1) outstanding)
    } else {
      WAIT_VM(0);                   // tail: only V(15) outstanding
    }
    BAR();                          // all waves' V DMA landed
    // PV phase: wave w owns q rows [w*16, w*16+16), full 128 kpos
#pragma unroll
    for (int kk = 0; kk < 4; ++kk) {
      int qr = w * 16 + l15;
      s8v a = *(const s8v*)&Ps[qr * 128 + (((kk * 4 + quad) ^ (qr & 15)) << 3)];
#pragma unroll
      for (int dt = 0; dt < 4; ++dt) {
        int d = dt * 16 + l15;
        s8v vb = *(const s8v*)&Vs[d * 128 + (((kk * 4 + quad) ^ (d & 15)) << 3)];
        o[dt] = __builtin_amdgcn_mfma_f32_16x16x32_bf16(a, vb, o[dt], 0, 0, 0);
      }
      lf = __builtin_amdgcn_mfma_f32_16x16x32_bf16(a, ones, lf, 0, 0, 0);
    }
    WAIT_LGKM0();                   // PV reads done
    BAR();                          // Vs, Ps free
    if (kt < 15) {
#pragma unroll
      for (int i = 0; i < 4; ++i) gl_lds16(vsrc + (kt + 1) * 128 + i * 32768, &Vs[(i * 4 + w) * 512]);
    }
  }

  // lf[r] = l for q = w*16 + quad*4 + r (replicated across l15). No reduce needed.
  float rv[4];
#pragma unroll
  for (int r = 0; r < 4; ++r) rv[r] = 1.0f / lf[r];
  if (l15 == 0) {
    f4v t; t[0] = rv[0]; t[1] = rv[1]; t[2] = rv[2]; t[3] = rv[3];
    *(f4v*)&rbuf[bh * 2048 + q0 + w * 16 + quad * 4] = t;
  }
#pragma unroll
  for (int dt = 0; dt < 4; ++dt)
#pragma unroll
    for (int r = 0; r < 4; ++r) {
      int sq = q0 + w * 16 + quad * 4 + r;
      ctx[((b * 2048 + sq) * 16 + h) * 64 + dt * 16 + l15] = b16(o[dt][r] * rv[r]);
    }
}

// ---------------- mean over heads of probs -> [b, q, k] fp32
// ONE barrier per h (dbuf; DMA h+1 issued after top barrier, waited next iter).
__global__ __launch_bounds__(256) void mean_probs(const short* __restrict__ Q, const short* __restrict__ K,
                                                  const float* __restrict__ rbuf, float* __restrict__ outm) {
  __shared__ __align__(16) short Qs[2][8192];   // [128 q][64 d] swizzled, dbuf
  __shared__ __align__(16) short Ks[2][8192];   // [128 k][64 d] swizzled, dbuf
  __shared__ __align__(16) float r_all[2048];   // [16 h][128 q]
  int nlin = blockIdx.x + 16 * (blockIdx.y + 16 * blockIdx.z);   // 0..1023
  int bid = (nlin & 7) * 128 + (nlin >> 3);                      // bijective (1024 % 8 == 0)
  const int k128 = bid & 15, q128 = (bid >> 4) & 15, b = bid >> 8;
  const int tid = threadIdx.x, w = tid >> 6, lane = tid & 63, quad = lane >> 4, l15 = lane & 15;
  f4v mn[2][8] = {};
  const int mrow = w * 8 + (lane >> 3);
  const int mck8 = ((lane & 7) ^ (lane >> 3)) << 3;
  const short* qsrc = Q + ((long)(b * 2048 + q128 * 128 + mrow) * 16) * 64 + mck8;
  const short* ksrc = K + ((long)(b * 2048 + k128 * 128 + mrow) * 16) * 64 + mck8;
  const float* rb = rbuf + (long)(b * 16) * 2048 + q128 * 128;
#pragma unroll
  for (int i = 0; i < 2; ++i) {
    int hh = i * 8 + w * 2 + (lane >> 5);
    gl_lds16((const short*)(rb + hh * 2048 + (lane & 31) * 4), (short*)r_all + (i * 4 + w) * 512);
  }
#pragma unroll
  for (int i = 0; i < 4; ++i) gl_lds16(qsrc + i * 32768, &Qs[0][(i * 4 + w) * 512]);
#pragma unroll
  for (int i = 0; i < 4; ++i) gl_lds16(ksrc + i * 32768, &Ks[0][(i * 4 + w) * 512]);

  for (int h = 0; h < 16; ++h) {
    const int cur = h & 1;
    WAIT_VM(0);     // h's loads (+r_all at h=0) landed (issued a full h-step ago)
    BAR();          // all waves: landed + done with buf cur^1
    if (h < 15) {
#pragma unroll
      for (int i = 0; i < 4; ++i) gl_lds16(qsrc + (h + 1) * 64 + i * 32768, &Qs[cur ^ 1][(i * 4 + w) * 512]);
#pragma unroll
      for (int i = 0; i < 4; ++i) gl_lds16(ksrc + (h + 1) * 64 + i * 32768, &Ks[cur ^ 1][(i * 4 + w) * 512]);
    }
    s8v aq[2][2];
#pragma unroll
    for (int qt = 0; qt < 2; ++qt) {
      int r = w * 32 + qt * 16 + l15;
      aq[qt][0] = *(const s8v*)&Qs[cur][r * 64 + ((quad ^ (r & 7)) << 3)];
      aq[qt][1] = *(const s8v*)&Qs[cur][r * 64 + (((4 + quad) ^ (r & 7)) << 3)];
    }
    float rr[2][4];
#pragma unroll
    for (int qt = 0; qt < 2; ++qt)
#pragma unroll
      for (int r = 0; r < 4; ++r) rr[qt][r] = r_all[h * 128 + w * 32 + qt * 16 + quad * 4 + r];
#pragma unroll
    for (int ktile = 0; ktile < 8; ++ktile) {
      int kr = ktile * 16 + l15;
      s8v b0 = *(const s8v*)&Ks[cur][kr * 64 + ((quad ^ (kr & 7)) << 3)];
      s8v b1 = *(const s8v*)&Ks[cur][kr * 64 + (((4 + quad) ^ (kr & 7)) << 3)];
#pragma unroll
      for (int qt = 0; qt < 2; ++qt) {
        f4v sc = {};
        sc = __builtin_amdgcn_mfma_f32_16x16x32_bf16(aq[qt][0], b0, sc, 0, 0, 0);
        sc = __builtin_amdgcn_mfma_f32_16x16x32_bf16(aq[qt][1], b1, sc, 0, 0, 0);
#pragma unroll
        for (int r = 0; r < 4; ++r)
          mn[qt][ktile][r] += fexp2(sc[r]) * rr[qt][r];
      }
    }
  }
#pragma unroll
  for (int qt = 0; qt < 2; ++qt)
#pragma unroll
    for (int ktile = 0; ktile < 8; ++ktile)
#pragma unroll
      for (int r = 0; r < 4; ++r) {
        long qrow = q128 * 128 + w * 32 + qt * 16 + quad * 4 + r;
        outm[((long)b * 2048 + qrow) * 2048 + k128 * 128 + ktile * 16 + l15] = mn[qt][ktile][r] * 0.0625f;
      }
}

extern "C" void kernel_launch(void* const* d_in, const int* in_sizes, int n_in,
                              void* d_out, int out_size, void* d_ws, size_t ws_size,
                              hipStream_t stream) {
  (void)in_sizes; (void)n_in; (void)out_size; (void)ws_size;
  const float* x  = (const float*)d_in[0];
  const float* Wq = (const float*)d_in[1];
  const float* bq = (const float*)d_in[2];
  const float* Wk = (const float*)d_in[3];
  const float* bk = (const float*)d_in[4];
  const float* Wv = (const float*)d_in[5];
  const float* bv = (const float*)d_in[6];
  const float* Wo = (const float*)d_in[7];
  const float* bo = (const float*)d_in[8];
  float* out  = (float*)d_out;
  float* outm = out + 8388608;

  char* ws = (char*)d_ws;
  short* xb  = (short*)(ws);                 // 16 MB (reused as ctx)
  short* Wqt = (short*)(ws + 16777216);      // Wqt,Wkt,Wvt,Wot contiguous 2MB each
  short* Wot = (short*)(ws + 23068672);
  short* Qb  = (short*)(ws + 25165824);      // Qb,Kb contiguous 16 MB each
  short* Kb  = (short*)(ws + 41943040);
  short* Vt  = (short*)(ws + 75497472);      // 16 MB, written directly by gemm_qkv
  float* rbuf = (float*)(ws + 58720256);     // in unused slot
  short* ctx = xb;                           // alias: xb dead after QKV GEMMs

  const float C2 = 0.18033688011112042f;     // (1/8) * log2(e), folded into Q projection

  prep<<<10240, 256, 0, stream>>>(x, xb, Wq, Wk, Wv, Wo, Wqt);
  gemm_qkv<<<dim3(24, 64), 256, 0, stream>>>(xb, Wqt, bq, bk, bv, Qb, Vt, C2);
  attn_ctx<<<dim3(32, 16, 4), 256, 0, stream>>>(Qb, Kb, Vt, rbuf, ctx);
  mean_probs<<<dim3(16, 16, 4), 256, 0, stream>>>(Qb, Kb, rbuf, outm);
  gemm128<<<dim3(8, 64), 256, 0, stream>>>(ctx, Wot, bo, out);
}

// Round 13
// 384.675 us; speedup vs baseline: 1.0951x; 1.0273x over previous
//
#include <hip/hip_runtime.h>

typedef __attribute__((ext_vector_type(8))) short s8v;
typedef __attribute__((ext_vector_type(4))) short s4v;
typedef __attribute__((ext_vector_type(4))) float f4v;

#define DEV __device__ __forceinline__

DEV short b16(float f) {
  unsigned u = __builtin_bit_cast(unsigned, f);
  u = (u + 0x7fffu + ((u >> 16) & 1u)) >> 16;
  return (short)u;
}

// packed f32x2 -> bf16x2 (RNE) as one uint
DEV unsigned pk2(float a, float b) {
#if __has_builtin(__builtin_amdgcn_cvt_pk_bf16_f32)
  auto p = __builtin_amdgcn_cvt_pk_bf16_f32(a, b);
  return __builtin_bit_cast(unsigned, p);
#else
  return (unsigned)(unsigned short)b16(a) | ((unsigned)(unsigned short)b16(b) << 16);
#endif
}

DEV float fexp2(float x) {
#if __has_builtin(__builtin_amdgcn_exp2f)
  return __builtin_amdgcn_exp2f(x);
#else
  return exp2f(x);
#endif
}

// async global->LDS, 16B per lane; lds base must be wave-uniform
DEV void gl_lds16(const short* g, short* l) {
  __builtin_amdgcn_global_load_lds((const __attribute__((address_space(1))) void*)g,
                                   (__attribute__((address_space(3))) void*)l, 16, 0, 0);
}

#define WAIT_VM(N) asm volatile("s_waitcnt vmcnt(" #N ")" ::: "memory")
#define WAIT_LGKM0() asm volatile("s_waitcnt lgkmcnt(0)" ::: "memory")
#define BAR() __builtin_amdgcn_s_barrier()

// ---------------- prep: fused cast x (blocks 0..8191) + wtrans x4 (blocks 8192..10239)
__global__ __launch_bounds__(256) void prep(const float* __restrict__ x, short* __restrict__ xb,
                                            const float* __restrict__ W0, const float* __restrict__ W1,
                                            const float* __restrict__ W2, const float* __restrict__ W3,
                                            short* __restrict__ Wt) {
  const int tid = threadIdx.x;
  if (blockIdx.x < 8192) {
    int i = blockIdx.x * 256 + tid;
    float4 v = ((const float4*)x)[i];
    s4v o; o.x = b16(v.x); o.y = b16(v.y); o.z = b16(v.z); o.w = b16(v.w);
    ((s4v*)xb)[i] = o;
  } else {
    int wid = blockIdx.x - 8192;
    const int mat = wid >> 9;
    const float* W = mat == 0 ? W0 : (mat == 1 ? W1 : (mat == 2 ? W2 : W3));
    short* out = Wt + (long)mat * 1048576;
    int id = (wid & 511) * 256 + tid;
    int k8 = id >> 10;
    int n  = id & 1023;
    s8v o;
#pragma unroll
    for (int j = 0; j < 8; ++j) o[j] = b16(W[(k8 * 8 + j) * 1024 + n]);
    *(s8v*)&out[n * 1024 + k8 * 8] = o;
  }
}

// ---------------- fused QKV GEMM, 1-barrier dbuf pipeline.
// V output written in Vt [b,h,d,s] layout via coalesced LDS-transpose. XCD swizzle.
__global__ __launch_bounds__(256) void gemm_qkv(const short* __restrict__ A,
                                                const short* __restrict__ Wt,
                                                const float* __restrict__ bq,
                                                const float* __restrict__ bk,
                                                const float* __restrict__ bv,
                                                short* __restrict__ Cb,
                                                short* __restrict__ Vt, float qscale) {
  __shared__ short AB[32768];                    // [buf][A:8192|B:8192] shorts, 64 KB
  int n = blockIdx.x + 24 * blockIdx.y;          // 0..1535
  int id = (n & 7) * 192 + (n >> 3);             // bijective (1536 % 8 == 0)
  const int nx = id % 24, my = id / 24;
  const int mat = nx >> 3;
  const short* Bt = Wt + (long)mat * 1048576;
  const float* bias = mat == 0 ? bq : (mat == 1 ? bk : bv);
  short* Cout = Cb + (long)mat * 8388608;
  const float scale = mat == 0 ? qscale : 1.0f;
  const int m0 = my * 128, n0 = (nx & 7) * 128;
  const int tid = threadIdx.x;
  const int w = tid >> 6, lane = tid & 63, quad = lane >> 4, l15 = lane & 15;
  const int wm = w >> 1, wn = w & 1;
  const int lr = lane >> 3, lc = (lane & 7) * 8;
  f4v acc[4][4] = {};
  // prologue: issue step 0 into buf 0
#pragma unroll
  for (int i = 0; i < 4; ++i) {
    int c = i * 4 + w;
    int r = c * 8 + lr;
    gl_lds16(&A[(m0 + r) * 1024 + lc], &AB[c * 512]);
    gl_lds16(&Bt[(n0 + r) * 1024 + lc], &AB[8192 + c * 512]);
  }
  for (int t = 0; t < 16; ++t) {
    const int cur = (t & 1) * 16384;
    WAIT_VM(0);        // step t's loads landed (issued a full step earlier)
    WAIT_LGKM0();
    BAR();             // all waves: data ready, prev buf free
    if (t < 15) {
      const int nxt = ((t + 1) & 1) * 16384;
      const int k0 = (t + 1) * 64;
#pragma unroll
      for (int i = 0; i < 4; ++i) {
        int c = i * 4 + w;
        int r = c * 8 + lr;
        gl_lds16(&A[(m0 + r) * 1024 + k0 + lc], &AB[nxt + c * 512]);
        gl_lds16(&Bt[(n0 + r) * 1024 + k0 + lc], &AB[nxt + 8192 + c * 512]);
      }
    }
    const short* As = &AB[cur];
    const short* Bs = &AB[cur + 8192];
#pragma unroll
    for (int kk = 0; kk < 2; ++kk) {
      s8v af[4], bf[4];
#pragma unroll
      for (int mt = 0; mt < 4; ++mt) af[mt] = *(const s8v*)&As[(wm * 64 + mt * 16 + l15) * 64 + kk * 32 + quad * 8];
#pragma unroll
      for (int nt = 0; nt < 4; ++nt) bf[nt] = *(const s8v*)&Bs[(wn * 64 + nt * 16 + l15) * 64 + kk * 32 + quad * 8];
#pragma unroll
      for (int mt = 0; mt < 4; ++mt)
#pragma unroll
        for (int nt = 0; nt < 4; ++nt)
          acc[mt][nt] = __builtin_amdgcn_mfma_f32_16x16x32_bf16(af[mt], bf[nt], acc[mt][nt], 0, 0, 0);
    }
  }
  if (mat == 2) {
    __syncthreads();   // all waves done with AB before T overwrite
    // transpose 128x128 tile in LDS: T[c 0..127][s 0..127], XOR-swizzled 8-short chunks
    short* T = AB;
#pragma unroll
    for (int nt = 0; nt < 4; ++nt) {
      const int c = wn * 64 + nt * 16 + l15;
      const float bcol = bias[n0 + c];
#pragma unroll
      for (int mt = 0; mt < 4; ++mt) {
        const int sr = wm * 64 + mt * 16 + quad * 4;
#pragma unroll
        for (int r = 0; r < 4; ++r) {
          int s = sr + r;
          T[c * 128 + ((((s >> 3) ^ (c & 15))) << 3) + (s & 7)] = b16(acc[mt][nt][r] + bcol);
        }
      }
    }
    __syncthreads();
    const int b = m0 >> 11, s0 = m0 & 2047, h0 = n0 >> 6;
#pragma unroll
    for (int i = 0; i < 8; ++i) {
      int unit = tid + i * 256;
      int c = unit >> 4, s8 = unit & 15;
      s8v v = *(const s8v*)&T[c * 128 + ((s8 ^ (c & 15)) << 3)];
      *(s8v*)&Vt[(((long)(b * 16 + h0 + (c >> 6)) * 64) + (c & 63)) * 2048 + s0 + s8 * 8] = v;
    }
  } else {
#pragma unroll
    for (int nt = 0; nt < 4; ++nt) {
      const int col = n0 + wn * 64 + nt * 16 + l15;
      const float bcol = bias[col];
#pragma unroll
      for (int mt = 0; mt < 4; ++mt)
#pragma unroll
        for (int r = 0; r < 4; ++r) {
          const int row = m0 + wm * 64 + mt * 16 + quad * 4 + r;
          Cout[row * 1024 + col] = b16((acc[mt][nt][r] + bcol) * scale);
        }
    }
  }
}

// ---------------- fused attention v8 (known-good): counted-vmcnt pipeline +
// l-via-MFMA + XCD swizzle. KVBLK=128, 3 blocks/CU. No setprio (measured harmful).
__global__ __launch_bounds__(256, 3) void attn_ctx(const short* __restrict__ Q, const short* __restrict__ K,
                                                   const short* __restrict__ Vt,
                                                   float* __restrict__ rbuf, short* __restrict__ ctx) {
  __shared__ __align__(16) char smem[49152];
  short* Ks = (short*)smem;                 // [128 kpos][64 d]   swizzled, 16384 B
  short* Vs = (short*)(smem + 16384);       // [64 d][128 kpos]   swizzled, 16384 B
  short* Ps = (short*)(smem + 32768);       // [64 q][128 kpos]   swizzled, 16384 B
  short* Qs = Ps;                           // alias: Qs dead after frag hoist
  int nlin = blockIdx.x + 32 * (blockIdx.y + 16 * blockIdx.z);   // 0..2047
  int bid = (nlin & 7) * 256 + (nlin >> 3);                      // bijective (2048 % 8 == 0)
  const int q64 = bid & 31, h = (bid >> 5) & 15, b = bid >> 9;
  const int tid = threadIdx.x, w = tid >> 6, lane = tid & 63, quad = lane >> 4, l15 = lane & 15;
  const int bh = b * 16 + h, q0 = q64 * 64;

  // stage Q tile (64x64) swizzled (reg roundtrip; once per kernel)
#pragma unroll
  for (int i = 0; i < 2; ++i) {
    int c = tid + i * 256;
    int r = c >> 3, cc = c & 7;
    *(s8v*)&Qs[r * 64 + (((cc ^ (r & 7))) << 3)] =
        *(const s8v*)&Q[((b * 2048 + q0 + r) * 16 + h) * 64 + cc * 8];
  }
  __syncthreads();   // full drain: vmcnt=0 after this
  // hoist Q fragments (B-operand of St = K·Q^T), all 64 q cols
  s8v qf[4][2];
#pragma unroll
  for (int nt = 0; nt < 4; ++nt) {
    int r = nt * 16 + l15;
    qf[nt][0] = *(const s8v*)&Qs[r * 64 + ((quad ^ (r & 7)) << 3)];
    qf[nt][1] = *(const s8v*)&Qs[r * 64 + (((4 + quad) ^ (r & 7)) << 3)];
  }
  const short* kbase = &K[((long)(b * 2048) * 16 + h) * 64];
  const short* vbase = &Vt[(long)(bh * 64) * 2048];
  const int krow = w * 8 + (lane >> 3);
  const short* ksrc = kbase + krow * 1024 + (((lane & 7) ^ (lane >> 3)) << 3);
  const int vrow = w * 4 + (lane >> 4);
  const short* vsrc = vbase + vrow * 2048 + (((lane & 15) ^ vrow) << 3);
  f4v o[4] = {};
  f4v lf = {};
  s8v ones;
#pragma unroll
  for (int j = 0; j < 8; ++j) ones[j] = (short)0x3F80;   // bf16 1.0

  // prologue: issue K(0) group (4), then V(0) group (4)
#pragma unroll
  for (int i = 0; i < 4; ++i) gl_lds16(ksrc + i * 32768, &Ks[(i * 4 + w) * 512]);
#pragma unroll
  for (int i = 0; i < 4; ++i) gl_lds16(vsrc + i * 32768, &Vs[(i * 4 + w) * 512]);
  WAIT_LGKM0();   // qf reads complete before first barrier

  for (int kt = 0; kt < 16; ++kt) {
    WAIT_VM(4);                     // own K(kt) retired (V(kt) may remain)
    BAR();                          // all waves' K DMA landed
    // score phase: wave w computes St rows kpos [w*32, w*32+32), all 64 q
#pragma unroll
    for (int mt = 0; mt < 2; ++mt) {
      int kr = w * 32 + mt * 16 + l15;
      s8v a0 = *(const s8v*)&Ks[kr * 64 + ((quad ^ (kr & 7)) << 3)];
      s8v a1 = *(const s8v*)&Ks[kr * 64 + (((4 + quad) ^ (kr & 7)) << 3)];
#pragma unroll
      for (int nt = 0; nt < 4; ++nt) {
        f4v st = {};
        st = __builtin_amdgcn_mfma_f32_16x16x32_bf16(a0, qf[nt][0], st, 0, 0, 0);
        st = __builtin_amdgcn_mfma_f32_16x16x32_bf16(a1, qf[nt][1], st, 0, 0, 0);
        float e0 = fexp2(st[0]), e1 = fexp2(st[1]);
        float e2 = fexp2(st[2]), e3 = fexp2(st[3]);
        uint2 pp; pp.x = pk2(e0, e1); pp.y = pk2(e2, e3);
        int q = nt * 16 + l15;
        int chunk = (w * 4 + mt * 2 + (quad >> 1)) ^ l15;
        *(uint2*)&Ps[q * 128 + (chunk << 3) + (quad & 1) * 4] = pp;
      }
    }
    WAIT_LGKM0();                   // Ps writes + Ks reads done
    BAR();                          // Ks free, Ps visible
    if (kt < 15) {
#pragma unroll
      for (int i = 0; i < 4; ++i) gl_lds16(ksrc + (kt + 1) * 131072 + i * 32768, &Ks[(i * 4 + w) * 512]);
      WAIT_VM(4);                   // V(kt) retired (K(kt+1) outstanding)
    } else {
      WAIT_VM(0);                   // tail: only V(15) outstanding
    }
    BAR();                          // all waves' V DMA landed
    // PV phase: wave w owns q rows [w*16, w*16+16), full 128 kpos
#pragma unroll
    for (int kk = 0; kk < 4; ++kk) {
      int qr = w * 16 + l15;
      s8v a = *(const s8v*)&Ps[qr * 128 + (((kk * 4 + quad) ^ (qr & 15)) << 3)];
#pragma unroll
      for (int dt = 0; dt < 4; ++dt) {
        int d = dt * 16 + l15;
        s8v vb = *(const s8v*)&Vs[d * 128 + (((kk * 4 + quad) ^ (d & 15)) << 3)];
        o[dt] = __builtin_amdgcn_mfma_f32_16x16x32_bf16(a, vb, o[dt], 0, 0, 0);
      }
      lf = __builtin_amdgcn_mfma_f32_16x16x32_bf16(a, ones, lf, 0, 0, 0);
    }
    WAIT_LGKM0();                   // PV reads done
    BAR();                          // Vs, Ps free
    if (kt < 15) {
#pragma unroll
      for (int i = 0; i < 4; ++i) gl_lds16(vsrc + (kt + 1) * 128 + i * 32768, &Vs[(i * 4 + w) * 512]);
    }
  }

  // lf[r] = l for q = w*16 + quad*4 + r (replicated across l15). No reduce needed.
  float rv[4];
#pragma unroll
  for (int r = 0; r < 4; ++r) rv[r] = 1.0f / lf[r];
  if (l15 == 0) {
    f4v t; t[0] = rv[0]; t[1] = rv[1]; t[2] = rv[2]; t[3] = rv[3];
    *(f4v*)&rbuf[bh * 2048 + q0 + w * 16 + quad * 4] = t;
  }
#pragma unroll
  for (int dt = 0; dt < 4; ++dt)
#pragma unroll
    for (int r = 0; r < 4; ++r) {
      int sq = q0 + w * 16 + quad * 4 + r;
      ctx[((b * 2048 + sq) * 16 + h) * 64 + dt * 16 + l15] = b16(o[dt][r] * rv[r]);
    }
}

// ---------------- tail_fused: gemm128 (blocks 0..511) + mean_probs (blocks 512..1535)
// The two have no data dependency (gemm reads ctx/Wot; mean_probs reads Qb/Kb/rbuf) —
// one launch lets the scheduler overlap MFMA-heavy gemm with exp-heavy mean_probs.
// LDS 72KB (max of both); both keep 2 blocks/CU. XCD swizzles preserved (offsets %8==0).
__global__ __launch_bounds__(256) void tail_fused(const short* __restrict__ A,
                                                  const short* __restrict__ Bt,
                                                  const float* __restrict__ bias,
                                                  float* __restrict__ Cout,
                                                  const short* __restrict__ Q,
                                                  const short* __restrict__ K,
                                                  const float* __restrict__ rbuf,
                                                  float* __restrict__ outm) {
  __shared__ __align__(16) char smem[73728];
  const int tid = threadIdx.x;
  const int w = tid >> 6, lane = tid & 63, quad = lane >> 4, l15 = lane & 15;
  if (blockIdx.x < 512) {
    // ---- gemm128 body (1-barrier dbuf pipeline; fp32 out; XCD swizzle) ----
    short* AB = (short*)smem;
    int n = blockIdx.x;                          // 0..511
    int id = (n & 7) * 64 + (n >> 3);            // bijective (512 % 8 == 0)
    const int m0 = (id >> 3) * 128, n0 = (id & 7) * 128;
    const int wm = w >> 1, wn = w & 1;
    const int lr = lane >> 3, lc = (lane & 7) * 8;
    f4v acc[4][4] = {};
#pragma unroll
    for (int i = 0; i < 4; ++i) {
      int c = i * 4 + w;
      int r = c * 8 + lr;
      gl_lds16(&A[(m0 + r) * 1024 + lc], &AB[c * 512]);
      gl_lds16(&Bt[(n0 + r) * 1024 + lc], &AB[8192 + c * 512]);
    }
    for (int t = 0; t < 16; ++t) {
      const int cur = (t & 1) * 16384;
      WAIT_VM(0);
      WAIT_LGKM0();
      BAR();
      if (t < 15) {
        const int nxt = ((t + 1) & 1) * 16384;
        const int k0 = (t + 1) * 64;
#pragma unroll
        for (int i = 0; i < 4; ++i) {
          int c = i * 4 + w;
          int r = c * 8 + lr;
          gl_lds16(&A[(m0 + r) * 1024 + k0 + lc], &AB[nxt + c * 512]);
          gl_lds16(&Bt[(n0 + r) * 1024 + k0 + lc], &AB[nxt + 8192 + c * 512]);
        }
      }
      const short* As = &AB[cur];
      const short* Bs = &AB[cur + 8192];
#pragma unroll
      for (int kk = 0; kk < 2; ++kk) {
        s8v af[4], bf[4];
#pragma unroll
        for (int mt = 0; mt < 4; ++mt) af[mt] = *(const s8v*)&As[(wm * 64 + mt * 16 + l15) * 64 + kk * 32 + quad * 8];
#pragma unroll
        for (int nt = 0; nt < 4; ++nt) bf[nt] = *(const s8v*)&Bs[(wn * 64 + nt * 16 + l15) * 64 + kk * 32 + quad * 8];
#pragma unroll
        for (int mt = 0; mt < 4; ++mt)
#pragma unroll
          for (int nt = 0; nt < 4; ++nt)
            acc[mt][nt] = __builtin_amdgcn_mfma_f32_16x16x32_bf16(af[mt], bf[nt], acc[mt][nt], 0, 0, 0);
      }
    }
#pragma unroll
    for (int nt = 0; nt < 4; ++nt) {
      const int col = n0 + wn * 64 + nt * 16 + l15;
      const float bcol = bias[col];
#pragma unroll
      for (int mt = 0; mt < 4; ++mt)
#pragma unroll
        for (int r = 0; r < 4; ++r) {
          const int row = m0 + wm * 64 + mt * 16 + quad * 4 + r;
          Cout[row * 1024 + col] = acc[mt][nt][r] + bcol;
        }
    }
  } else {
    // ---- mean_probs body (ONE barrier per h; dbuf; rbuf preloaded; XCD swizzle) ----
    short* QsB = (short*)smem;                   // [2][8192] shorts, 32 KB
    short* KsB = (short*)(smem + 32768);         // [2][8192] shorts, 32 KB
    float* r_all = (float*)(smem + 65536);       // [16 h][128 q], 8 KB
    int nlin = blockIdx.x - 512;                 // 0..1023
    int bid = (nlin & 7) * 128 + (nlin >> 3);    // bijective (1024 % 8 == 0)
    const int k128 = bid & 15, q128 = (bid >> 4) & 15, b = bid >> 8;
    f4v mn[2][8] = {};
    const int mrow = w * 8 + (lane >> 3);
    const int mck8 = ((lane & 7) ^ (lane >> 3)) << 3;
    const short* qsrc = Q + ((long)(b * 2048 + q128 * 128 + mrow) * 16) * 64 + mck8;
    const short* ksrc = K + ((long)(b * 2048 + k128 * 128 + mrow) * 16) * 64 + mck8;
    const float* rb = rbuf + (long)(b * 16) * 2048 + q128 * 128;
#pragma unroll
    for (int i = 0; i < 2; ++i) {
      int hh = i * 8 + w * 2 + (lane >> 5);
      gl_lds16((const short*)(rb + hh * 2048 + (lane & 31) * 4), (short*)r_all + (i * 4 + w) * 512);
    }
#pragma unroll
    for (int i = 0; i < 4; ++i) gl_lds16(qsrc + i * 32768, QsB + (i * 4 + w) * 512);
#pragma unroll
    for (int i = 0; i < 4; ++i) gl_lds16(ksrc + i * 32768, KsB + (i * 4 + w) * 512);

    for (int h = 0; h < 16; ++h) {
      const int cur = h & 1;
      const short* Qsc = QsB + cur * 8192;
      const short* Ksc = KsB + cur * 8192;
      WAIT_VM(0);     // h's loads (+r_all at h=0) landed (issued a full h-step ago)
      BAR();          // all waves: landed + done with buf cur^1
      if (h < 15) {
        short* Qsn = QsB + (cur ^ 1) * 8192;
        short* Ksn = KsB + (cur ^ 1) * 8192;
#pragma unroll
        for (int i = 0; i < 4; ++i) gl_lds16(qsrc + (h + 1) * 64 + i * 32768, Qsn + (i * 4 + w) * 512);
#pragma unroll
        for (int i = 0; i < 4; ++i) gl_lds16(ksrc + (h + 1) * 64 + i * 32768, Ksn + (i * 4 + w) * 512);
      }
      s8v aq[2][2];
#pragma unroll
      for (int qt = 0; qt < 2; ++qt) {
        int r = w * 32 + qt * 16 + l15;
        aq[qt][0] = *(const s8v*)&Qsc[r * 64 + ((quad ^ (r & 7)) << 3)];
        aq[qt][1] = *(const s8v*)&Qsc[r * 64 + (((4 + quad) ^ (r & 7)) << 3)];
      }
      float rr[2][4];
#pragma unroll
      for (int qt = 0; qt < 2; ++qt)
#pragma unroll
        for (int r = 0; r < 4; ++r) rr[qt][r] = r_all[h * 128 + w * 32 + qt * 16 + quad * 4 + r];
#pragma unroll
      for (int ktile = 0; ktile < 8; ++ktile) {
        int kr = ktile * 16 + l15;
        s8v b0 = *(const s8v*)&Ksc[kr * 64 + ((quad ^ (kr & 7)) << 3)];
        s8v b1 = *(const s8v*)&Ksc[kr * 64 + (((4 + quad) ^ (kr & 7)) << 3)];
#pragma unroll
        for (int qt = 0; qt < 2; ++qt) {
          f4v sc = {};
          sc = __builtin_amdgcn_mfma_f32_16x16x32_bf16(aq[qt][0], b0, sc, 0, 0, 0);
          sc = __builtin_amdgcn_mfma_f32_16x16x32_bf16(aq[qt][1], b1, sc, 0, 0, 0);
#pragma unroll
          for (int r = 0; r < 4; ++r)
            mn[qt][ktile][r] += fexp2(sc[r]) * rr[qt][r];
        }
      }
    }
#pragma unroll
    for (int qt = 0; qt < 2; ++qt)
#pragma unroll
      for (int ktile = 0; ktile < 8; ++ktile)
#pragma unroll
        for (int r = 0; r < 4; ++r) {
          long qrow = q128 * 128 + w * 32 + qt * 16 + quad * 4 + r;
          outm[((long)b * 2048 + qrow) * 2048 + k128 * 128 + ktile * 16 + l15] = mn[qt][ktile][r] * 0.0625f;
        }
  }
}

extern "C" void kernel_launch(void* const* d_in, const int* in_sizes, int n_in,
                              void* d_out, int out_size, void* d_ws, size_t ws_size,
                              hipStream_t stream) {
  (void)in_sizes; (void)n_in; (void)out_size; (void)ws_size;
  const float* x  = (const float*)d_in[0];
  const float* Wq = (const float*)d_in[1];
  const float* bq = (const float*)d_in[2];
  const float* Wk = (const float*)d_in[3];
  const float* bk = (const float*)d_in[4];
  const float* Wv = (const float*)d_in[5];
  const float* bv = (const float*)d_in[6];
  const float* Wo = (const float*)d_in[7];
  const float* bo = (const float*)d_in[8];
  float* out  = (float*)d_out;
  float* outm = out + 8388608;

  char* ws = (char*)d_ws;
  short* xb  = (short*)(ws);                 // 16 MB (reused as ctx)
  short* Wqt = (short*)(ws + 16777216);      // Wqt,Wkt,Wvt,Wot contiguous 2MB each
  short* Wot = (short*)(ws + 23068672);
  short* Qb  = (short*)(ws + 25165824);      // Qb,Kb contiguous 16 MB each
  short* Kb  = (short*)(ws + 41943040);
  short* Vt  = (short*)(ws + 75497472);      // 16 MB, written directly by gemm_qkv
  float* rbuf = (float*)(ws + 58720256);     // in unused slot
  short* ctx = xb;                           // alias: xb dead after QKV GEMMs

  const float C2 = 0.18033688011112042f;     // (1/8) * log2(e), folded into Q projection

  prep<<<10240, 256, 0, stream>>>(x, xb, Wq, Wk, Wv, Wo, Wqt);
  gemm_qkv<<<dim3(24, 64), 256, 0, stream>>>(xb, Wqt, bq, bk, bv, Qb, Vt, C2);
  attn_ctx<<<dim3(32, 16, 4), 256, 0, stream>>>(Qb, Kb, Vt, rbuf, ctx);
  tail_fused<<<1536, 256, 0, stream>>>(ctx, Wot, bo, out, Qb, Kb, rbuf, outm);
}

// Round 14
// 372.352 us; speedup vs baseline: 1.1314x; 1.0331x over previous
//
#include <hip/hip_runtime.h>

typedef __attribute__((ext_vector_type(8))) short s8v;
typedef __attribute__((ext_vector_type(4))) short s4v;
typedef __attribute__((ext_vector_type(4))) float f4v;

#define DEV __device__ __forceinline__

DEV short b16(float f) {
  unsigned u = __builtin_bit_cast(unsigned, f);
  u = (u + 0x7fffu + ((u >> 16) & 1u)) >> 16;
  return (short)u;
}

// packed f32x2 -> bf16x2 (RNE) as one uint
DEV unsigned pk2(float a, float b) {
#if __has_builtin(__builtin_amdgcn_cvt_pk_bf16_f32)
  auto p = __builtin_amdgcn_cvt_pk_bf16_f32(a, b);
  return __builtin_bit_cast(unsigned, p);
#else
  return (unsigned)(unsigned short)b16(a) | ((unsigned)(unsigned short)b16(b) << 16);
#endif
}

DEV float fexp2(float x) {
#if __has_builtin(__builtin_amdgcn_exp2f)
  return __builtin_amdgcn_exp2f(x);
#else
  return exp2f(x);
#endif
}

// async global->LDS, 16B per lane; lds base must be wave-uniform
DEV void gl_lds16(const short* g, short* l) {
  __builtin_amdgcn_global_load_lds((const __attribute__((address_space(1))) void*)g,
                                   (__attribute__((address_space(3))) void*)l, 16, 0, 0);
}

#define WAIT_VM(N) asm volatile("s_waitcnt vmcnt(" #N ")" ::: "memory")
#define WAIT_LGKM0() asm volatile("s_waitcnt lgkmcnt(0)" ::: "memory")
#define BAR() __builtin_amdgcn_s_barrier()

// ---------------- prep: fused cast x (blocks 0..8191) + wtrans x4 (blocks 8192..10239)
__global__ __launch_bounds__(256) void prep(const float* __restrict__ x, short* __restrict__ xb,
                                            const float* __restrict__ W0, const float* __restrict__ W1,
                                            const float* __restrict__ W2, const float* __restrict__ W3,
                                            short* __restrict__ Wt) {
  const int tid = threadIdx.x;
  if (blockIdx.x < 8192) {
    int i = blockIdx.x * 256 + tid;
    float4 v = ((const float4*)x)[i];
    s4v o; o.x = b16(v.x); o.y = b16(v.y); o.z = b16(v.z); o.w = b16(v.w);
    ((s4v*)xb)[i] = o;
  } else {
    int wid = blockIdx.x - 8192;
    const int mat = wid >> 9;
    const float* W = mat == 0 ? W0 : (mat == 1 ? W1 : (mat == 2 ? W2 : W3));
    short* out = Wt + (long)mat * 1048576;
    int id = (wid & 511) * 256 + tid;
    int k8 = id >> 10;
    int n  = id & 1023;
    s8v o;
#pragma unroll
    for (int j = 0; j < 8; ++j) o[j] = b16(W[(k8 * 8 + j) * 1024 + n]);
    *(s8v*)&out[n * 1024 + k8 * 8] = o;
  }
}

// ---------------- fused QKV GEMM, BK=32, 3-buffer rotation, counted vmcnt(4)
// (2 steps prefetched ahead). 48KB LDS -> 3 blocks/CU. V output written in
// Vt [b,h,d,s] layout via coalesced LDS-transpose. XCD swizzle.
__global__ __launch_bounds__(256, 3) void gemm_qkv(const short* __restrict__ A,
                                                   const short* __restrict__ Wt,
                                                   const float* __restrict__ bq,
                                                   const float* __restrict__ bk,
                                                   const float* __restrict__ bv,
                                                   short* __restrict__ Cb,
                                                   short* __restrict__ Vt, float qscale) {
  __shared__ short AB[24576];                    // 3 bufs x (A:4096 | B:4096) shorts, 48 KB
  int n = blockIdx.x + 24 * blockIdx.y;          // 0..1535
  int id = (n & 7) * 192 + (n >> 3);             // bijective (1536 % 8 == 0)
  const int nx = id % 24, my = id / 24;
  const int mat = nx >> 3;
  const short* Bt = Wt + (long)mat * 1048576;
  const float* bias = mat == 0 ? bq : (mat == 1 ? bk : bv);
  short* Cout = Cb + (long)mat * 8388608;
  const float scale = mat == 0 ? qscale : 1.0f;
  const int m0 = my * 128, n0 = (nx & 7) * 128;
  const int tid = threadIdx.x;
  const int w = tid >> 6, lane = tid & 63, quad = lane >> 4, l15 = lane & 15;
  const int wm = w >> 1, wn = w & 1;
  const int lrA = lane >> 2, lcA = (lane & 3) * 8;   // BK=32: 16 rows x 4 chunks per wave-call
  f4v acc[4][4] = {};
  // prologue: issue steps 0 (buf0) and 1 (buf1); 2 calls A + 2 calls B each
#pragma unroll
  for (int t0 = 0; t0 < 2; ++t0) {
    short* Ab = AB + t0 * 8192;
    const int k0 = t0 * 32;
#pragma unroll
    for (int i = 0; i < 2; ++i) {
      int rb = (i * 4 + w) * 16;
      gl_lds16(&A[(m0 + rb + lrA) * 1024 + k0 + lcA], Ab + (i * 4 + w) * 512);
      gl_lds16(&Bt[(n0 + rb + lrA) * 1024 + k0 + lcA], Ab + 4096 + (i * 4 + w) * 512);
    }
  }
  int cb = 0;
  for (int t = 0; t < 32; ++t) {
    short* Ab = AB + cb * 8192;
    if (t < 30) { WAIT_VM(4); } else { WAIT_VM(0); }   // drain step t; keep t+1 in flight
    WAIT_LGKM0();
    BAR();             // all waves: step t landed; buf (cb+2)%3 free (compute t-1 done)
    if (t < 30) {
      const int nb = cb >= 1 ? cb - 1 : 2;             // (cb+2)%3
      short* An = AB + nb * 8192;
      const int k0 = (t + 2) * 32;
#pragma unroll
      for (int i = 0; i < 2; ++i) {
        int rb = (i * 4 + w) * 16;
        gl_lds16(&A[(m0 + rb + lrA) * 1024 + k0 + lcA], An + (i * 4 + w) * 512);
        gl_lds16(&Bt[(n0 + rb + lrA) * 1024 + k0 + lcA], An + 4096 + (i * 4 + w) * 512);
      }
    }
    const short* As = Ab;
    const short* Bs = Ab + 4096;
    s8v af[4], bf[4];
#pragma unroll
    for (int mt = 0; mt < 4; ++mt) af[mt] = *(const s8v*)&As[(wm * 64 + mt * 16 + l15) * 32 + quad * 8];
#pragma unroll
    for (int nt = 0; nt < 4; ++nt) bf[nt] = *(const s8v*)&Bs[(wn * 64 + nt * 16 + l15) * 32 + quad * 8];
#pragma unroll
    for (int mt = 0; mt < 4; ++mt)
#pragma unroll
      for (int nt = 0; nt < 4; ++nt)
        acc[mt][nt] = __builtin_amdgcn_mfma_f32_16x16x32_bf16(af[mt], bf[nt], acc[mt][nt], 0, 0, 0);
    cb = cb == 2 ? 0 : cb + 1;
  }
  if (mat == 2) {
    __syncthreads();   // all waves done with AB before T overwrite
    // transpose 128x128 tile in LDS: T[c 0..127][s 0..127], XOR-swizzled 8-short chunks
    short* T = AB;
#pragma unroll
    for (int nt = 0; nt < 4; ++nt) {
      const int c = wn * 64 + nt * 16 + l15;
      const float bcol = bias[n0 + c];
#pragma unroll
      for (int mt = 0; mt < 4; ++mt) {
        const int sr = wm * 64 + mt * 16 + quad * 4;
#pragma unroll
        for (int r = 0; r < 4; ++r) {
          int s = sr + r;
          T[c * 128 + ((((s >> 3) ^ (c & 15))) << 3) + (s & 7)] = b16(acc[mt][nt][r] + bcol);
        }
      }
    }
    __syncthreads();
    const int b = m0 >> 11, s0 = m0 & 2047, h0 = n0 >> 6;
#pragma unroll
    for (int i = 0; i < 8; ++i) {
      int unit = tid + i * 256;
      int c = unit >> 4, s8 = unit & 15;
      s8v v = *(const s8v*)&T[c * 128 + ((s8 ^ (c & 15)) << 3)];
      *(s8v*)&Vt[(((long)(b * 16 + h0 + (c >> 6)) * 64) + (c & 63)) * 2048 + s0 + s8 * 8] = v;
    }
  } else {
#pragma unroll
    for (int nt = 0; nt < 4; ++nt) {
      const int col = n0 + wn * 64 + nt * 16 + l15;
      const float bcol = bias[col];
#pragma unroll
      for (int mt = 0; mt < 4; ++mt)
#pragma unroll
        for (int r = 0; r < 4; ++r) {
          const int row = m0 + wm * 64 + mt * 16 + quad * 4 + r;
          Cout[row * 1024 + col] = b16((acc[mt][nt][r] + bcol) * scale);
        }
    }
  }
}

// ---------------- fused attention v8 (known-good): counted-vmcnt pipeline +
// l-via-MFMA + XCD swizzle. KVBLK=128, 3 blocks/CU. No setprio (measured harmful).
__global__ __launch_bounds__(256, 3) void attn_ctx(const short* __restrict__ Q, const short* __restrict__ K,
                                                   const short* __restrict__ Vt,
                                                   float* __restrict__ rbuf, short* __restrict__ ctx) {
  __shared__ __align__(16) char smem[49152];
  short* Ks = (short*)smem;                 // [128 kpos][64 d]   swizzled, 16384 B
  short* Vs = (short*)(smem + 16384);       // [64 d][128 kpos]   swizzled, 16384 B
  short* Ps = (short*)(smem + 32768);       // [64 q][128 kpos]   swizzled, 16384 B
  short* Qs = Ps;                           // alias: Qs dead after frag hoist
  int nlin = blockIdx.x + 32 * (blockIdx.y + 16 * blockIdx.z);   // 0..2047
  int bid = (nlin & 7) * 256 + (nlin >> 3);                      // bijective (2048 % 8 == 0)
  const int q64 = bid & 31, h = (bid >> 5) & 15, b = bid >> 9;
  const int tid = threadIdx.x, w = tid >> 6, lane = tid & 63, quad = lane >> 4, l15 = lane & 15;
  const int bh = b * 16 + h, q0 = q64 * 64;

  // stage Q tile (64x64) swizzled (reg roundtrip; once per kernel)
#pragma unroll
  for (int i = 0; i < 2; ++i) {
    int c = tid + i * 256;
    int r = c >> 3, cc = c & 7;
    *(s8v*)&Qs[r * 64 + (((cc ^ (r & 7))) << 3)] =
        *(const s8v*)&Q[((b * 2048 + q0 + r) * 16 + h) * 64 + cc * 8];
  }
  __syncthreads();   // full drain: vmcnt=0 after this
  // hoist Q fragments (B-operand of St = K·Q^T), all 64 q cols
  s8v qf[4][2];
#pragma unroll
  for (int nt = 0; nt < 4; ++nt) {
    int r = nt * 16 + l15;
    qf[nt][0] = *(const s8v*)&Qs[r * 64 + ((quad ^ (r & 7)) << 3)];
    qf[nt][1] = *(const s8v*)&Qs[r * 64 + (((4 + quad) ^ (r & 7)) << 3)];
  }
  const short* kbase = &K[((long)(b * 2048) * 16 + h) * 64];
  const short* vbase = &Vt[(long)(bh * 64) * 2048];
  const int krow = w * 8 + (lane >> 3);
  const short* ksrc = kbase + krow * 1024 + (((lane & 7) ^ (lane >> 3)) << 3);
  const int vrow = w * 4 + (lane >> 4);
  const short* vsrc = vbase + vrow * 2048 + (((lane & 15) ^ vrow) << 3);
  f4v o[4] = {};
  f4v lf = {};
  s8v ones;
#pragma unroll
  for (int j = 0; j < 8; ++j) ones[j] = (short)0x3F80;   // bf16 1.0

  // prologue: issue K(0) group (4), then V(0) group (4)
#pragma unroll
  for (int i = 0; i < 4; ++i) gl_lds16(ksrc + i * 32768, &Ks[(i * 4 + w) * 512]);
#pragma unroll
  for (int i = 0; i < 4; ++i) gl_lds16(vsrc + i * 32768, &Vs[(i * 4 + w) * 512]);
  WAIT_LGKM0();   // qf reads complete before first barrier

  for (int kt = 0; kt < 16; ++kt) {
    WAIT_VM(4);                     // own K(kt) retired (V(kt) may remain)
    BAR();                          // all waves' K DMA landed
    // score phase: wave w computes St rows kpos [w*32, w*32+32), all 64 q
#pragma unroll
    for (int mt = 0; mt < 2; ++mt) {
      int kr = w * 32 + mt * 16 + l15;
      s8v a0 = *(const s8v*)&Ks[kr * 64 + ((quad ^ (kr & 7)) << 3)];
      s8v a1 = *(const s8v*)&Ks[kr * 64 + (((4 + quad) ^ (kr & 7)) << 3)];
#pragma unroll
      for (int nt = 0; nt < 4; ++nt) {
        f4v st = {};
        st = __builtin_amdgcn_mfma_f32_16x16x32_bf16(a0, qf[nt][0], st, 0, 0, 0);
        st = __builtin_amdgcn_mfma_f32_16x16x32_bf16(a1, qf[nt][1], st, 0, 0, 0);
        float e0 = fexp2(st[0]), e1 = fexp2(st[1]);
        float e2 = fexp2(st[2]), e3 = fexp2(st[3]);
        uint2 pp; pp.x = pk2(e0, e1); pp.y = pk2(e2, e3);
        int q = nt * 16 + l15;
        int chunk = (w * 4 + mt * 2 + (quad >> 1)) ^ l15;
        *(uint2*)&Ps[q * 128 + (chunk << 3) + (quad & 1) * 4] = pp;
      }
    }
    WAIT_LGKM0();                   // Ps writes + Ks reads done
    BAR();                          // Ks free, Ps visible
    if (kt < 15) {
#pragma unroll
      for (int i = 0; i < 4; ++i) gl_lds16(ksrc + (kt + 1) * 131072 + i * 32768, &Ks[(i * 4 + w) * 512]);
      WAIT_VM(4);                   // V(kt) retired (K(kt+1) outstanding)
    } else {
      WAIT_VM(0);                   // tail: only V(15) outstanding
    }
    BAR();                          // all waves' V DMA landed
    // PV phase: wave w owns q rows [w*16, w*16+16), full 128 kpos
#pragma unroll
    for (int kk = 0; kk < 4; ++kk) {
      int qr = w * 16 + l15;
      s8v a = *(const s8v*)&Ps[qr * 128 + (((kk * 4 + quad) ^ (qr & 15)) << 3)];
#pragma unroll
      for (int dt = 0; dt < 4; ++dt) {
        int d = dt * 16 + l15;
        s8v vb = *(const s8v*)&Vs[d * 128 + (((kk * 4 + quad) ^ (d & 15)) << 3)];
        o[dt] = __builtin_amdgcn_mfma_f32_16x16x32_bf16(a, vb, o[dt], 0, 0, 0);
      }
      lf = __builtin_amdgcn_mfma_f32_16x16x32_bf16(a, ones, lf, 0, 0, 0);
    }
    WAIT_LGKM0();                   // PV reads done
    BAR();                          // Vs, Ps free
    if (kt < 15) {
#pragma unroll
      for (int i = 0; i < 4; ++i) gl_lds16(vsrc + (kt + 1) * 128 + i * 32768, &Vs[(i * 4 + w) * 512]);
    }
  }

  // lf[r] = l for q = w*16 + quad*4 + r (replicated across l15). No reduce needed.
  float rv[4];
#pragma unroll
  for (int r = 0; r < 4; ++r) rv[r] = 1.0f / lf[r];
  if (l15 == 0) {
    f4v t; t[0] = rv[0]; t[1] = rv[1]; t[2] = rv[2]; t[3] = rv[3];
    *(f4v*)&rbuf[bh * 2048 + q0 + w * 16 + quad * 4] = t;
  }
#pragma unroll
  for (int dt = 0; dt < 4; ++dt)
#pragma unroll
    for (int r = 0; r < 4; ++r) {
      int sq = q0 + w * 16 + quad * 4 + r;
      ctx[((b * 2048 + sq) * 16 + h) * 64 + dt * 16 + l15] = b16(o[dt][r] * rv[r]);
    }
}

// ---------------- tail_fused: gemm128 (blocks 0..511) + mean_probs (blocks 512..1535)
// No data dependency between the two; one launch overlaps MFMA-heavy gemm with
// exp-heavy mean_probs. LDS 72KB; both keep 2 blocks/CU. XCD swizzles preserved.
__global__ __launch_bounds__(256) void tail_fused(const short* __restrict__ A,
                                                  const short* __restrict__ Bt,
                                                  const float* __restrict__ bias,
                                                  float* __restrict__ Cout,
                                                  const short* __restrict__ Q,
                                                  const short* __restrict__ K,
                                                  const float* __restrict__ rbuf,
                                                  float* __restrict__ outm) {
  __shared__ __align__(16) char smem[73728];
  const int tid = threadIdx.x;
  const int w = tid >> 6, lane = tid & 63, quad = lane >> 4, l15 = lane & 15;
  if (blockIdx.x < 512) {
    // ---- gemm128 body (1-barrier dbuf pipeline; fp32 out; XCD swizzle) ----
    short* AB = (short*)smem;
    int n = blockIdx.x;                          // 0..511
    int id = (n & 7) * 64 + (n >> 3);            // bijective (512 % 8 == 0)
    const int m0 = (id >> 3) * 128, n0 = (id & 7) * 128;
    const int wm = w >> 1, wn = w & 1;
    const int lr = lane >> 3, lc = (lane & 7) * 8;
    f4v acc[4][4] = {};
#pragma unroll
    for (int i = 0; i < 4; ++i) {
      int c = i * 4 + w;
      int r = c * 8 + lr;
      gl_lds16(&A[(m0 + r) * 1024 + lc], &AB[c * 512]);
      gl_lds16(&Bt[(n0 + r) * 1024 + lc], &AB[8192 + c * 512]);
    }
    for (int t = 0; t < 16; ++t) {
      const int cur = (t & 1) * 16384;
      WAIT_VM(0);
      WAIT_LGKM0();
      BAR();
      if (t < 15) {
        const int nxt = ((t + 1) & 1) * 16384;
        const int k0 = (t + 1) * 64;
#pragma unroll
        for (int i = 0; i < 4; ++i) {
          int c = i * 4 + w;
          int r = c * 8 + lr;
          gl_lds16(&A[(m0 + r) * 1024 + k0 + lc], &AB[nxt + c * 512]);
          gl_lds16(&Bt[(n0 + r) * 1024 + k0 + lc], &AB[nxt + 8192 + c * 512]);
        }
      }
      const short* As = &AB[cur];
      const short* Bs = &AB[cur + 8192];
#pragma unroll
      for (int kk = 0; kk < 2; ++kk) {
        s8v af[4], bf[4];
#pragma unroll
        for (int mt = 0; mt < 4; ++mt) af[mt] = *(const s8v*)&As[(wm * 64 + mt * 16 + l15) * 64 + kk * 32 + quad * 8];
#pragma unroll
        for (int nt = 0; nt < 4; ++nt) bf[nt] = *(const s8v*)&Bs[(wn * 64 + nt * 16 + l15) * 64 + kk * 32 + quad * 8];
#pragma unroll
        for (int mt = 0; mt < 4; ++mt)
#pragma unroll
          for (int nt = 0; nt < 4; ++nt)
            acc[mt][nt] = __builtin_amdgcn_mfma_f32_16x16x32_bf16(af[mt], bf[nt], acc[mt][nt], 0, 0, 0);
      }
    }
#pragma unroll
    for (int nt = 0; nt < 4; ++nt) {
      const int col = n0 + wn * 64 + nt * 16 + l15;
      const float bcol = bias[col];
#pragma unroll
      for (int mt = 0; mt < 4; ++mt)
#pragma unroll
        for (int r = 0; r < 4; ++r) {
          const int row = m0 + wm * 64 + mt * 16 + quad * 4 + r;
          Cout[row * 1024 + col] = acc[mt][nt][r] + bcol;
        }
    }
  } else {
    // ---- mean_probs body (ONE barrier per h; dbuf; rbuf preloaded; XCD swizzle) ----
    short* QsB = (short*)smem;                   // [2][8192] shorts, 32 KB
    short* KsB = (short*)(smem + 32768);         // [2][8192] shorts, 32 KB
    float* r_all = (float*)(smem + 65536);       // [16 h][128 q], 8 KB
    int nlin = blockIdx.x - 512;                 // 0..1023
    int bid = (nlin & 7) * 128 + (nlin >> 3);    // bijective (1024 % 8 == 0)
    const int k128 = bid & 15, q128 = (bid >> 4) & 15, b = bid >> 8;
    f4v mn[2][8] = {};
    const int mrow = w * 8 + (lane >> 3);
    const int mck8 = ((lane & 7) ^ (lane >> 3)) << 3;
    const short* qsrc = Q + ((long)(b * 2048 + q128 * 128 + mrow) * 16) * 64 + mck8;
    const short* ksrc = K + ((long)(b * 2048 + k128 * 128 + mrow) * 16) * 64 + mck8;
    const float* rb = rbuf + (long)(b * 16) * 2048 + q128 * 128;
#pragma unroll
    for (int i = 0; i < 2; ++i) {
      int hh = i * 8 + w * 2 + (lane >> 5);
      gl_lds16((const short*)(rb + hh * 2048 + (lane & 31) * 4), (short*)r_all + (i * 4 + w) * 512);
    }
#pragma unroll
    for (int i = 0; i < 4; ++i) gl_lds16(qsrc + i * 32768, QsB + (i * 4 + w) * 512);
#pragma unroll
    for (int i = 0; i < 4; ++i) gl_lds16(ksrc + i * 32768, KsB + (i * 4 + w) * 512);

    for (int h = 0; h < 16; ++h) {
      const int cur = h & 1;
      const short* Qsc = QsB + cur * 8192;
      const short* Ksc = KsB + cur * 8192;
      WAIT_VM(0);     // h's loads (+r_all at h=0) landed (issued a full h-step ago)
      BAR();          // all waves: landed + done with buf cur^1
      if (h < 15) {
        short* Qsn = QsB + (cur ^ 1) * 8192;
        short* Ksn = KsB + (cur ^ 1) * 8192;
#pragma unroll
        for (int i = 0; i < 4; ++i) gl_lds16(qsrc + (h + 1) * 64 + i * 32768, Qsn + (i * 4 + w) * 512);
#pragma unroll
        for (int i = 0; i < 4; ++i) gl_lds16(ksrc + (h + 1) * 64 + i * 32768, Ksn + (i * 4 + w) * 512);
      }
      s8v aq[2][2];
#pragma unroll
      for (int qt = 0; qt < 2; ++qt) {
        int r = w * 32 + qt * 16 + l15;
        aq[qt][0] = *(const s8v*)&Qsc[r * 64 + ((quad ^ (r & 7)) << 3)];
        aq[qt][1] = *(const s8v*)&Qsc[r * 64 + (((4 + quad) ^ (r & 7)) << 3)];
      }
      float rr[2][4];
#pragma unroll
      for (int qt = 0; qt < 2; ++qt)
#pragma unroll
        for (int r = 0; r < 4; ++r) rr[qt][r] = r_all[h * 128 + w * 32 + qt * 16 + quad * 4 + r];
#pragma unroll
      for (int ktile = 0; ktile < 8; ++ktile) {
        int kr = ktile * 16 + l15;
        s8v b0 = *(const s8v*)&Ksc[kr * 64 + ((quad ^ (kr & 7)) << 3)];
        s8v b1 = *(const s8v*)&Ksc[kr * 64 + (((4 + quad) ^ (kr & 7)) << 3)];
#pragma unroll
        for (int qt = 0; qt < 2; ++qt) {
          f4v sc = {};
          sc = __builtin_amdgcn_mfma_f32_16x16x32_bf16(aq[qt][0], b0, sc, 0, 0, 0);
          sc = __builtin_amdgcn_mfma_f32_16x16x32_bf16(aq[qt][1], b1, sc, 0, 0, 0);
#pragma unroll
          for (int r = 0; r < 4; ++r)
            mn[qt][ktile][r] += fexp2(sc[r]) * rr[qt][r];
        }
      }
    }
#pragma unroll
    for (int qt = 0; qt < 2; ++qt)
#pragma unroll
      for (int ktile = 0; ktile < 8; ++ktile)
#pragma unroll
        for (int r = 0; r < 4; ++r) {
          long qrow = q128 * 128 + w * 32 + qt * 16 + quad * 4 + r;
          outm[((long)b * 2048 + qrow) * 2048 + k128 * 128 + ktile * 16 + l15] = mn[qt][ktile][r] * 0.0625f;
        }
  }
}

extern "C" void kernel_launch(void* const* d_in, const int* in_sizes, int n_in,
                              void* d_out, int out_size, void* d_ws, size_t ws_size,
                              hipStream_t stream) {
  (void)in_sizes; (void)n_in; (void)out_size; (void)ws_size;
  const float* x  = (const float*)d_in[0];
  const float* Wq = (const float*)d_in[1];
  const float* bq = (const float*)d_in[2];
  const float* Wk = (const float*)d_in[3];
  const float* bk = (const float*)d_in[4];
  const float* Wv = (const float*)d_in[5];
  const float* bv = (const float*)d_in[6];
  const float* Wo = (const float*)d_in[7];
  const float* bo = (const float*)d_in[8];
  float* out  = (float*)d_out;
  float* outm = out + 8388608;

  char* ws = (char*)d_ws;
  short* xb  = (short*)(ws);                 // 16 MB (reused as ctx)
  short* Wqt = (short*)(ws + 16777216);      // Wqt,Wkt,Wvt,Wot contiguous 2MB each
  short* Wot = (short*)(ws + 23068672);
  short* Qb  = (short*)(ws + 25165824);      // Qb,Kb contiguous 16 MB each
  short* Kb  = (short*)(ws + 41943040);
  short* Vt  = (short*)(ws + 75497472);      // 16 MB, written directly by gemm_qkv
  float* rbuf = (float*)(ws + 58720256);     // in unused slot
  short* ctx = xb;                           // alias: xb dead after QKV GEMMs

  const float C2 = 0.18033688011112042f;     // (1/8) * log2(e), folded into Q projection

  prep<<<10240, 256, 0, stream>>>(x, xb, Wq, Wk, Wv, Wo, Wqt);
  gemm_qkv<<<dim3(24, 64), 256, 0, stream>>>(xb, Wqt, bq, bk, bv, Qb, Vt, C2);
  attn_ctx<<<dim3(32, 16, 4), 256, 0, stream>>>(Qb, Kb, Vt, rbuf, ctx);
  tail_fused<<<1536, 256, 0, stream>>>(ctx, Wot, bo, out, Qb, Kb, rbuf, outm);
}